// Round 1
// baseline (977.425 us; speedup 1.0000x reference)
//
#include <hip/hip_runtime.h>
#include <math.h>

#define NN 50000
#define NE 800000
#define HD 128
#define NG 256

__device__ __forceinline__ float wave_allsum(float v) {
#pragma unroll
  for (int m = 1; m < 64; m <<= 1) v += __shfl_xor(v, m, 64);
  return v;
}

// ---------------- xw = x@gcn_w ; xl = x@pam_w + pam_b ----------------
// 16 nodes per block, 128 threads (thread = output channel). x reads are
// wave-uniform -> scalar loads; weight reads coalesced across threads.
__global__ __launch_bounds__(128) void k_lin(const float* __restrict__ x,
                                             const float* __restrict__ gw,
                                             const float* __restrict__ pw,
                                             const float* __restrict__ pb,
                                             float* __restrict__ xw,
                                             float* __restrict__ xl) {
  const int h = threadIdx.x;
  const int n0 = blockIdx.x * 16;
  float ag[16], ap[16];
#pragma unroll
  for (int r = 0; r < 16; ++r) { ag[r] = 0.f; ap[r] = 0.f; }
  for (int k = 0; k < HD; ++k) {
    const float wg = gw[k * HD + h];
    const float wp = pw[k * HD + h];
#pragma unroll
    for (int r = 0; r < 16; ++r) {
      const float xv = x[(n0 + r) * HD + k];
      ag[r] = fmaf(xv, wg, ag[r]);
      ap[r] = fmaf(xv, wp, ap[r]);
    }
  }
  const float bias = pb[h];
#pragma unroll
  for (int r = 0; r < 16; ++r) {
    xw[(n0 + r) * HD + h] = ag[r];
    xl[(n0 + r) * HD + h] = ap[r] + bias;
  }
}

// ---------------- CSR build ----------------
__global__ __launch_bounds__(256) void k_hist(const int* __restrict__ ei,
                                              int* __restrict__ cnt) {
  int e = blockIdx.x * 256 + threadIdx.x;
  if (e < NE) atomicAdd(&cnt[ei[NE + e]], 1);
}

// single-block exclusive scan over NN counts
__global__ __launch_bounds__(1024) void k_scan(const int* __restrict__ cnt,
                                               int* __restrict__ offs) {
  __shared__ int sums[1024];
  const int t = threadIdx.x;
  const int chunk = (NN + 1023) >> 10;  // 49
  const int b = t * chunk;
  const int e = min(b + chunk, NN);
  int s = 0;
  for (int i = b; i < e; ++i) s += cnt[i];
  sums[t] = s;
  __syncthreads();
  for (int d = 1; d < 1024; d <<= 1) {
    int add = (t >= d) ? sums[t - d] : 0;
    __syncthreads();
    sums[t] += add;
    __syncthreads();
  }
  int pre = (t > 0) ? sums[t - 1] : 0;
  for (int i = b; i < e; ++i) {
    offs[i] = pre;
    pre += cnt[i];
  }
}

__global__ __launch_bounds__(256) void k_scatter(const int* __restrict__ ei,
                                                 const int* __restrict__ offs,
                                                 int* __restrict__ cursor,
                                                 int* __restrict__ csr_src) {
  int e = blockIdx.x * 256 + threadIdx.x;
  if (e < NE) {
    int d = ei[NE + e];
    int slot = atomicAdd(&cursor[d], 1);
    csr_src[offs[d] + slot] = ei[e];
  }
}

__global__ __launch_bounds__(256) void k_dinv(const int* __restrict__ cnt,
                                              float* __restrict__ dinv) {
  int i = blockIdx.x * 256 + threadIdx.x;
  if (i < NN) dinv[i] = __builtin_amdgcn_rsqf((float)cnt[i] + 1.0f);
}

// ---------------- per-node edge aggregation (1 wave / node) ----------------
// outputs: gl = relu(gcn) ; t = sum att*g(delta) ; P = sum att*x_j + (sum att)*b2
__global__ __launch_bounds__(256) void k_agg(
    const float* __restrict__ xw, const float* __restrict__ xl,
    const float* __restrict__ pos, const float* __restrict__ dinv,
    const int* __restrict__ csr_src, const int* __restrict__ offs,
    const int* __restrict__ cnt, const float* __restrict__ att_w,
    const float* __restrict__ att_b, const float* __restrict__ pm_w1,
    const float* __restrict__ pm_b1, const float* __restrict__ pm_b2,
    const float* __restrict__ gcn_b, float* __restrict__ gl,
    float* __restrict__ tb, float* __restrict__ Pb) {
  const int wave = threadIdx.x >> 6, lane = threadIdx.x & 63;
  const int i = blockIdx.x * 4 + wave;
  if (i >= NN) return;
  const int c0 = lane, c1 = lane + 64;

  const float w10 = pm_w1[c0], w11 = pm_w1[HD + c0], w12 = pm_w1[2 * HD + c0];
  const float v10 = pm_w1[c1], v11 = pm_w1[HD + c1], v12 = pm_w1[2 * HD + c1];
  const float b10 = pm_b1[c0], b11 = pm_b1[c1];
  const float awj0 = att_w[HD + c0], awj1 = att_w[HD + c1];

  const float xi0 = xl[i * HD + c0], xi1 = xl[i * HD + c1];
  const float ai = wave_allsum(fmaf(xi0, att_w[c0], xi1 * att_w[c1])) + att_b[0];
  const float pix = pos[i * 3], piy = pos[i * 3 + 1], piz = pos[i * 3 + 2];
  const float di = dinv[i];

  float t0 = 0.f, t1 = 0.f, u0 = 0.f, u1 = 0.f, ga0 = 0.f, ga1 = 0.f, sa = 0.f;
  const int b = offs[i], e = b + cnt[i];
  for (int k = b; k < e; ++k) {
    const int s = csr_src[k];
    const float xj0 = xl[s * HD + c0], xj1 = xl[s * HD + c1];
    float att = wave_allsum(fmaf(xj0, awj0, xj1 * awj1)) + ai;
    att = __builtin_amdgcn_rcpf(1.f + __expf(-att));
    const float dx = pix - pos[s * 3];
    const float dy = piy - pos[s * 3 + 1];
    const float dz = piz - pos[s * 3 + 2];
    const float g0 = fmaxf(fmaf(dz, w12, fmaf(dy, w11, fmaf(dx, w10, b10))), 0.f);
    const float g1 = fmaxf(fmaf(dz, v12, fmaf(dy, v11, fmaf(dx, v10, b11))), 0.f);
    t0 = fmaf(att, g0, t0);
    t1 = fmaf(att, g1, t1);
    u0 = fmaf(att, xj0, u0);
    u1 = fmaf(att, xj1, u1);
    sa += att;
    const float ds_ = dinv[s];
    ga0 = fmaf(ds_, xw[s * HD + c0], ga0);
    ga1 = fmaf(ds_, xw[s * HD + c1], ga1);
  }
  const float xwi0 = xw[i * HD + c0], xwi1 = xw[i * HD + c1];
  const float gcn0 = fmaf(di, fmaf(di, xwi0, ga0), gcn_b[c0]);
  const float gcn1 = fmaf(di, fmaf(di, xwi1, ga1), gcn_b[c1]);
  gl[i * HD + c0] = fmaxf(gcn0, 0.f);
  gl[i * HD + c1] = fmaxf(gcn1, 0.f);
  tb[i * HD + c0] = t0;
  tb[i * HD + c1] = t1;
  Pb[i * HD + c0] = fmaf(sa, pm_b2[c0], u0);
  Pb[i * HD + c1] = fmaf(sa, pm_b2[c1], u1);
}

// ---------------- local = relu(P + t@pm_w2)  (in-place over t) -------------
__global__ __launch_bounds__(128) void k_lgemm(const float* __restrict__ tin,
                                               const float* __restrict__ Pb,
                                               const float* __restrict__ w2,
                                               float* __restrict__ localf) {
  const int h = threadIdx.x;
  const int n0 = blockIdx.x * 16;
  float acc[16];
#pragma unroll
  for (int r = 0; r < 16; ++r) acc[r] = 0.f;
  for (int k = 0; k < HD; ++k) {
    const float w = w2[k * HD + h];
#pragma unroll
    for (int r = 0; r < 16; ++r) acc[r] = fmaf(tin[(n0 + r) * HD + k], w, acc[r]);
  }
  __syncthreads();  // tin may alias localf: all reads before any write
#pragma unroll
  for (int r = 0; r < 16; ++r)
    localf[(n0 + r) * HD + h] = fmaxf(acc[r] + Pb[(n0 + r) * HD + h], 0.f);
}

// ------- fused = relu([gl,local]@fus_w + fus_b), pooled += (atomics) -------
__global__ __launch_bounds__(128) void k_fused(const float* __restrict__ gl,
                                               const float* __restrict__ localf,
                                               const float* __restrict__ fw,
                                               const float* __restrict__ fb,
                                               const int* __restrict__ batch,
                                               float* __restrict__ pooled) {
  const int h = threadIdx.x;
  const int n0 = blockIdx.x * 16;
  float acc[16];
#pragma unroll
  for (int r = 0; r < 16; ++r) acc[r] = 0.f;
  for (int k = 0; k < HD; ++k) {
    const float w = fw[k * HD + h];
#pragma unroll
    for (int r = 0; r < 16; ++r) acc[r] = fmaf(gl[(n0 + r) * HD + k], w, acc[r]);
  }
  for (int k = 0; k < HD; ++k) {
    const float w = fw[(HD + k) * HD + h];
#pragma unroll
    for (int r = 0; r < 16; ++r)
      acc[r] = fmaf(localf[(n0 + r) * HD + k], w, acc[r]);
  }
  const float bias = fb[h];
#pragma unroll
  for (int r = 0; r < 16; ++r) {
    const int g = batch[n0 + r];
    atomicAdd(&pooled[g * HD + h], fmaxf(acc[r] + bias, 0.f));
  }
}

__global__ __launch_bounds__(256) void k_counts(const int* __restrict__ batch,
                                                float* __restrict__ counts) {
  int i = blockIdx.x * 256 + threadIdx.x;
  if (i < NN) atomicAdd(&counts[batch[i]], 1.f);
}

// ---------------- head: out = relu(pooled/cnt @ l1)@l2 ----------------
__global__ __launch_bounds__(64) void k_head(const float* __restrict__ pooled,
                                             const float* __restrict__ counts,
                                             const float* __restrict__ l1w,
                                             const float* __restrict__ l1b,
                                             const float* __restrict__ l2w,
                                             const float* __restrict__ l2b,
                                             float* __restrict__ out) {
  const int g = blockIdx.x, j = threadIdx.x;
  const float inv = __builtin_amdgcn_rcpf(fmaxf(counts[g], 1.f));
  float acc = l1b[j];
  for (int k = 0; k < HD; ++k)
    acc = fmaf(pooled[g * HD + k] * inv, l1w[k * 64 + j], acc);
  float v = fmaxf(acc, 0.f) * l2w[j];
  v = wave_allsum(v);
  if (j == 0) out[g] = v + l2b[0];
}

extern "C" void kernel_launch(void* const* d_in, const int* in_sizes, int n_in,
                              void* d_out, int out_size, void* d_ws,
                              size_t ws_size, hipStream_t stream) {
  const float* x = (const float*)d_in[0];
  const float* pos = (const float*)d_in[1];
  const int* ei = (const int*)d_in[2];
  const int* batch = (const int*)d_in[3];
  const float* gcn_w = (const float*)d_in[4];
  const float* gcn_b = (const float*)d_in[5];
  const float* pam_w = (const float*)d_in[6];
  const float* pam_b = (const float*)d_in[7];
  const float* pm_w1 = (const float*)d_in[8];
  const float* pm_b1 = (const float*)d_in[9];
  const float* pm_w2 = (const float*)d_in[10];
  const float* pm_b2 = (const float*)d_in[11];
  const float* att_w = (const float*)d_in[12];
  const float* att_b = (const float*)d_in[13];
  const float* fus_w = (const float*)d_in[14];
  const float* fus_b = (const float*)d_in[15];
  const float* l1_w = (const float*)d_in[16];
  const float* l1_b = (const float*)d_in[17];
  const float* l2_w = (const float*)d_in[18];
  const float* l2_b = (const float*)d_in[19];
  float* out = (float*)d_out;

  size_t off = 0;
  auto alloc = [&](size_t elems) {
    void* p = (char*)d_ws + off;
    off += ((elems * 4 + 255) / 256) * 256;
    return p;
  };
  float* xw = (float*)alloc((size_t)NN * HD);
  float* xl = (float*)alloc((size_t)NN * HD);
  float* tb = (float*)alloc((size_t)NN * HD);  // later aliased as localf
  float* Pb = (float*)alloc((size_t)NN * HD);
  float* gl = (float*)alloc((size_t)NN * HD);
  float* dinv = (float*)alloc(NN);
  float* pooled = (float*)alloc((size_t)NG * HD);
  float* counts = (float*)alloc(NG);
  int* cnt = (int*)alloc(NN);
  int* cursor = (int*)alloc(NN);
  int* offs = (int*)alloc(NN);
  int* csr_src = (int*)alloc(NE);

  hipMemsetAsync(cnt, 0, NN * 4, stream);
  hipMemsetAsync(cursor, 0, NN * 4, stream);
  hipMemsetAsync(pooled, 0, NG * HD * 4, stream);
  hipMemsetAsync(counts, 0, NG * 4, stream);

  k_lin<<<NN / 16, 128, 0, stream>>>(x, gcn_w, pam_w, pam_b, xw, xl);
  k_hist<<<(NE + 255) / 256, 256, 0, stream>>>(ei, cnt);
  k_scan<<<1, 1024, 0, stream>>>(cnt, offs);
  k_scatter<<<(NE + 255) / 256, 256, 0, stream>>>(ei, offs, cursor, csr_src);
  k_dinv<<<(NN + 255) / 256, 256, 0, stream>>>(cnt, dinv);
  k_agg<<<(NN + 3) / 4, 256, 0, stream>>>(xw, xl, pos, dinv, csr_src, offs, cnt,
                                          att_w, att_b, pm_w1, pm_b1, pm_b2,
                                          gcn_b, gl, tb, Pb);
  k_lgemm<<<NN / 16, 128, 0, stream>>>(tb, Pb, pm_w2, tb);
  k_fused<<<NN / 16, 128, 0, stream>>>(gl, tb, fus_w, fus_b, batch, pooled);
  k_counts<<<(NN + 255) / 256, 256, 0, stream>>>(batch, counts);
  k_head<<<NG, 64, 0, stream>>>(pooled, counts, l1_w, l1_b, l2_w, l2_b, out);
}

// Round 2
// 541.762 us; speedup vs baseline: 1.8042x; 1.8042x over previous
//
#include <hip/hip_runtime.h>
#include <math.h>

#define NN 50000
#define NE 800000
#define HD 128
#define NG 256

__device__ __forceinline__ float wave_allsum(float v) {
#pragma unroll
  for (int m = 1; m < 64; m <<= 1) v += __shfl_xor(v, m, 64);
  return v;
}

__device__ __forceinline__ float bcastf(float v, int t) {
  return __int_as_float(__builtin_amdgcn_readlane(__float_as_int(v), t));
}

// ---------------------------------------------------------------------------
// Tiled fp32 GEMM core: C[128x128] tile, BK=16, 256 threads, 8x8 micro-tile.
// A is [rows][HD] row-major (split across two sources at k==asplit for the
// concatenated-K case). B is [K][HD] row-major. Micro-tile columns/rows are
// {g*4..+3} U {64+g*4..+3} for bank-conflict-free LDS reads.
// ---------------------------------------------------------------------------
__device__ __forceinline__ void gemm_tile(const float* __restrict__ A0,
                                          const float* __restrict__ A1,
                                          int asplit, const float* __restrict__ B,
                                          int K, int n0, float acc[8][8],
                                          float* A_lds, float* B_lds) {
  const int t = threadIdx.x;
  const int tx = t & 15, ty = t >> 4;
  const int arow = t >> 1;
  const int akb = (t & 1) * 8;
  const int bkb = t >> 5;
  const int bc = (t & 31) * 4;

  for (int k0 = 0; k0 < K; k0 += 16) {
    const float* As = (k0 < asplit) ? A0 : A1;
    const int kc = (k0 < asplit) ? k0 : k0 - asplit;
    __syncthreads();
    {  // stage A (transposed: A_lds[k][row])
      const int row = min(n0 + arow, NN - 1);
      const float4* src = (const float4*)&As[(size_t)row * HD + kc + akb];
      const float4 v0 = src[0], v1 = src[1];
      A_lds[(akb + 0) * 128 + arow] = v0.x;
      A_lds[(akb + 1) * 128 + arow] = v0.y;
      A_lds[(akb + 2) * 128 + arow] = v0.z;
      A_lds[(akb + 3) * 128 + arow] = v0.w;
      A_lds[(akb + 4) * 128 + arow] = v1.x;
      A_lds[(akb + 5) * 128 + arow] = v1.y;
      A_lds[(akb + 6) * 128 + arow] = v1.z;
      A_lds[(akb + 7) * 128 + arow] = v1.w;
    }
    // stage B (B_lds[k][c])
    *(float4*)&B_lds[bkb * 128 + bc] =
        *(const float4*)&B[(size_t)(k0 + bkb) * HD + bc];
    *(float4*)&B_lds[(bkb + 8) * 128 + bc] =
        *(const float4*)&B[(size_t)(k0 + bkb + 8) * HD + bc];
    __syncthreads();
#pragma unroll
    for (int k = 0; k < 16; ++k) {
      const float4 a0 = *(const float4*)&A_lds[k * 128 + ty * 4];
      const float4 a1 = *(const float4*)&A_lds[k * 128 + 64 + ty * 4];
      const float4 b0 = *(const float4*)&B_lds[k * 128 + tx * 4];
      const float4 b1 = *(const float4*)&B_lds[k * 128 + 64 + tx * 4];
      const float ar[8] = {a0.x, a0.y, a0.z, a0.w, a1.x, a1.y, a1.z, a1.w};
      const float br[8] = {b0.x, b0.y, b0.z, b0.w, b1.x, b1.y, b1.z, b1.w};
#pragma unroll
      for (int r = 0; r < 8; ++r)
#pragma unroll
        for (int c = 0; c < 8; ++c) acc[r][c] = fmaf(ar[r], br[c], acc[r][c]);
    }
  }
}

// ---------------- xw = x@gcn_w (y=0) ; xl = x@pam_w + pam_b (y=1) ----------
__global__ __launch_bounds__(256) void k_lin(const float* __restrict__ x,
                                             const float* __restrict__ gw,
                                             const float* __restrict__ pw,
                                             const float* __restrict__ pb,
                                             float* __restrict__ xw,
                                             float* __restrict__ xl) {
  __shared__ float A_lds[16 * 128], B_lds[16 * 128];
  const int y = blockIdx.y;
  const float* B = y ? pw : gw;
  float* O = y ? xl : xw;
  const int n0 = blockIdx.x * 128;
  const int tx = threadIdx.x & 15, ty = threadIdx.x >> 4;
  float acc[8][8] = {};
  gemm_tile(x, x, HD, B, HD, n0, acc, A_lds, B_lds);
  float4 b0 = {0, 0, 0, 0}, b1 = {0, 0, 0, 0};
  if (y) {
    b0 = *(const float4*)&pb[tx * 4];
    b1 = *(const float4*)&pb[64 + tx * 4];
  }
#pragma unroll
  for (int rh = 0; rh < 2; ++rh)
#pragma unroll
    for (int j = 0; j < 4; ++j) {
      const int row = n0 + rh * 64 + ty * 4 + j;
      if (row < NN) {
        const int r = rh * 4 + j;
        float4 o0 = {acc[r][0] + b0.x, acc[r][1] + b0.y, acc[r][2] + b0.z,
                     acc[r][3] + b0.w};
        float4 o1 = {acc[r][4] + b1.x, acc[r][5] + b1.y, acc[r][6] + b1.z,
                     acc[r][7] + b1.w};
        *(float4*)&O[(size_t)row * HD + tx * 4] = o0;
        *(float4*)&O[(size_t)row * HD + 64 + tx * 4] = o1;
      }
    }
}

// ---------------- CSR build ----------------
__global__ __launch_bounds__(256) void k_hist(const int* __restrict__ ei,
                                              int* __restrict__ cnt) {
  int e = blockIdx.x * 256 + threadIdx.x;
  if (e < NE) atomicAdd(&cnt[ei[NE + e]], 1);
}

__global__ __launch_bounds__(1024) void k_scan(const int* __restrict__ cnt,
                                               int* __restrict__ offs) {
  __shared__ int sums[1024];
  const int t = threadIdx.x;
  const int chunk = (NN + 1023) >> 10;
  const int b = t * chunk;
  const int e = min(b + chunk, NN);
  int s = 0;
  for (int i = b; i < e; ++i) s += cnt[i];
  sums[t] = s;
  __syncthreads();
  for (int d = 1; d < 1024; d <<= 1) {
    int add = (t >= d) ? sums[t - d] : 0;
    __syncthreads();
    sums[t] += add;
    __syncthreads();
  }
  int pre = (t > 0) ? sums[t - 1] : 0;
  for (int i = b; i < e; ++i) {
    offs[i] = pre;
    pre += cnt[i];
  }
}

__global__ __launch_bounds__(256) void k_scatter(const int* __restrict__ ei,
                                                 const int* __restrict__ offs,
                                                 int* __restrict__ cursor,
                                                 int* __restrict__ csr_src) {
  int e = blockIdx.x * 256 + threadIdx.x;
  if (e < NE) {
    int d = ei[NE + e];
    int slot = atomicAdd(&cursor[d], 1);
    csr_src[offs[d] + slot] = ei[e];
  }
}

__global__ __launch_bounds__(256) void k_dinv(const int* __restrict__ cnt,
                                              float* __restrict__ dinv) {
  int i = blockIdx.x * 256 + threadIdx.x;
  if (i < NN) dinv[i] = __builtin_amdgcn_rsqf((float)cnt[i] + 1.0f);
}

// -------- per-node attention-dot precompute: ai = xl.wi + b, aj = xl.wj -----
__global__ __launch_bounds__(256) void k_attpre(const float* __restrict__ xl,
                                                const float* __restrict__ att_w,
                                                const float* __restrict__ att_b,
                                                float* __restrict__ ai,
                                                float* __restrict__ aj) {
  const int wave = threadIdx.x >> 6, lane = threadIdx.x & 63;
  const int i = blockIdx.x * 4 + wave;
  if (i >= NN) return;
  const float2 v = *(const float2*)&xl[(size_t)i * HD + lane * 2];
  const float2 wi = *(const float2*)&att_w[lane * 2];
  const float2 wj = *(const float2*)&att_w[HD + lane * 2];
  float si = wave_allsum(fmaf(v.x, wi.x, v.y * wi.y));
  float sj = wave_allsum(fmaf(v.x, wj.x, v.y * wj.y));
  if (lane == 0) {
    ai[i] = si + att_b[0];
    aj[i] = sj;
  }
}

// ---------------- per-node edge aggregation (1 wave / node) ----------------
__global__ __launch_bounds__(256) void k_agg(
    const float* __restrict__ xw, const float* __restrict__ xl,
    const float* __restrict__ pos, const float* __restrict__ dinv,
    const int* __restrict__ csr_src, const int* __restrict__ offs,
    const int* __restrict__ cnt, const float* __restrict__ ai_arr,
    const float* __restrict__ aj_arr, const float* __restrict__ pm_w1,
    const float* __restrict__ pm_b1, const float* __restrict__ pm_b2,
    const float* __restrict__ gcn_b, float* __restrict__ gl,
    float* __restrict__ tb, float* __restrict__ Pb) {
  const int wave = threadIdx.x >> 6, lane = threadIdx.x & 63;
  const int i = blockIdx.x * 4 + wave;
  if (i >= NN) return;
  const int c0 = lane * 2;

  const float2 w1x = *(const float2*)&pm_w1[c0];
  const float2 w1y = *(const float2*)&pm_w1[HD + c0];
  const float2 w1z = *(const float2*)&pm_w1[2 * HD + c0];
  const float2 b1 = *(const float2*)&pm_b1[c0];
  const float ai = ai_arr[i];
  const float pix = pos[i * 3], piy = pos[i * 3 + 1], piz = pos[i * 3 + 2];
  const float di = dinv[i];

  float t0 = 0.f, t1 = 0.f, u0 = 0.f, u1 = 0.f, ga0 = 0.f, ga1 = 0.f, sa = 0.f;
  const int b = offs[i], e = b + cnt[i];
  for (int base = b; base < e; base += 64) {
    const int m = min(64, e - base);
    const int sk = csr_src[base + ((lane < m) ? lane : 0)];
    float attk = ai + aj_arr[sk];
    attk = __builtin_amdgcn_rcpf(1.f + __expf(-attk));
    const float dsk = dinv[sk];
    const float dxk = pix - pos[sk * 3];
    const float dyk = piy - pos[sk * 3 + 1];
    const float dzk = piz - pos[sk * 3 + 2];
    for (int t = 0; t < m; ++t) {
      const int s = __builtin_amdgcn_readlane(sk, t);
      const float att = bcastf(attk, t);
      const float ds = bcastf(dsk, t);
      const float dx = bcastf(dxk, t);
      const float dy = bcastf(dyk, t);
      const float dz = bcastf(dzk, t);
      const float2 xj = *(const float2*)&xl[(size_t)s * HD + c0];
      const float2 xwj = *(const float2*)&xw[(size_t)s * HD + c0];
      const float g0 =
          fmaxf(fmaf(dz, w1z.x, fmaf(dy, w1y.x, fmaf(dx, w1x.x, b1.x))), 0.f);
      const float g1 =
          fmaxf(fmaf(dz, w1z.y, fmaf(dy, w1y.y, fmaf(dx, w1x.y, b1.y))), 0.f);
      t0 = fmaf(att, g0, t0);
      t1 = fmaf(att, g1, t1);
      u0 = fmaf(att, xj.x, u0);
      u1 = fmaf(att, xj.y, u1);
      sa += att;
      ga0 = fmaf(ds, xwj.x, ga0);
      ga1 = fmaf(ds, xwj.y, ga1);
    }
  }
  const float2 xwi = *(const float2*)&xw[(size_t)i * HD + c0];
  const float2 gb = *(const float2*)&gcn_b[c0];
  float2 og;
  og.x = fmaxf(fmaf(di, fmaf(di, xwi.x, ga0), gb.x), 0.f);
  og.y = fmaxf(fmaf(di, fmaf(di, xwi.y, ga1), gb.y), 0.f);
  *(float2*)&gl[(size_t)i * HD + c0] = og;
  float2 ot = {t0, t1};
  *(float2*)&tb[(size_t)i * HD + c0] = ot;
  const float2 pb2 = *(const float2*)&pm_b2[c0];
  float2 op = {fmaf(sa, pb2.x, u0), fmaf(sa, pb2.y, u1)};
  *(float2*)&Pb[(size_t)i * HD + c0] = op;
}

// ---------------- local = relu(P + t@pm_w2) (written into Pb) --------------
__global__ __launch_bounds__(256) void k_lgemm(const float* __restrict__ tin,
                                               const float* __restrict__ w2,
                                               float* __restrict__ Pb) {
  __shared__ float A_lds[16 * 128], B_lds[16 * 128];
  const int n0 = blockIdx.x * 128;
  const int tx = threadIdx.x & 15, ty = threadIdx.x >> 4;
  float acc[8][8] = {};
  gemm_tile(tin, tin, HD, w2, HD, n0, acc, A_lds, B_lds);
#pragma unroll
  for (int rh = 0; rh < 2; ++rh)
#pragma unroll
    for (int j = 0; j < 4; ++j) {
      const int row = n0 + rh * 64 + ty * 4 + j;
      if (row < NN) {
        const int r = rh * 4 + j;
        float* p0 = &Pb[(size_t)row * HD + tx * 4];
        float* p1 = &Pb[(size_t)row * HD + 64 + tx * 4];
        const float4 q0 = *(const float4*)p0;
        const float4 q1 = *(const float4*)p1;
        float4 o0 = {fmaxf(acc[r][0] + q0.x, 0.f), fmaxf(acc[r][1] + q0.y, 0.f),
                     fmaxf(acc[r][2] + q0.z, 0.f), fmaxf(acc[r][3] + q0.w, 0.f)};
        float4 o1 = {fmaxf(acc[r][4] + q1.x, 0.f), fmaxf(acc[r][5] + q1.y, 0.f),
                     fmaxf(acc[r][6] + q1.z, 0.f), fmaxf(acc[r][7] + q1.w, 0.f)};
        *(float4*)p0 = o0;
        *(float4*)p1 = o1;
      }
    }
}

// ------ fused = relu([gl,local]@fus_w + fus_b); segment-pool into pooled ----
__global__ __launch_bounds__(256) void k_fused(const float* __restrict__ gl,
                                               const float* __restrict__ localf,
                                               const float* __restrict__ fw,
                                               const float* __restrict__ fb,
                                               const int* __restrict__ batch,
                                               float* __restrict__ pooled) {
  __shared__ float smem[128 * 128];
  __shared__ int batch_lds[128];
  float* A_lds = smem;
  float* B_lds = smem + 16 * 128;
  const int n0 = blockIdx.x * 128;
  const int t = threadIdx.x;
  const int tx = t & 15, ty = t >> 4;
  float acc[8][8] = {};
  gemm_tile(gl, localf, HD, fw, 2 * HD, n0, acc, A_lds, B_lds);

  const float4 fb0 = *(const float4*)&fb[tx * 4];
  const float4 fb1 = *(const float4*)&fb[64 + tx * 4];
  __syncthreads();  // done reading A/B tiles; reuse smem as C
#pragma unroll
  for (int rh = 0; rh < 2; ++rh)
#pragma unroll
    for (int j = 0; j < 4; ++j) {
      const int rl = rh * 64 + ty * 4 + j;
      const int r = rh * 4 + j;
      float4 o0 = {fmaxf(acc[r][0] + fb0.x, 0.f), fmaxf(acc[r][1] + fb0.y, 0.f),
                   fmaxf(acc[r][2] + fb0.z, 0.f), fmaxf(acc[r][3] + fb0.w, 0.f)};
      float4 o1 = {fmaxf(acc[r][4] + fb1.x, 0.f), fmaxf(acc[r][5] + fb1.y, 0.f),
                   fmaxf(acc[r][6] + fb1.z, 0.f), fmaxf(acc[r][7] + fb1.w, 0.f)};
      *(float4*)&smem[rl * 128 + tx * 4] = o0;
      *(float4*)&smem[rl * 128 + 64 + tx * 4] = o1;
    }
  if (t < 128) batch_lds[t] = (n0 + t < NN) ? batch[n0 + t] : -1;
  __syncthreads();

  // segment-reduce columns over sorted batch ids (two row-halves in parallel)
  const int col = t & 127;
  const int r0 = (t >> 7) * 64, r1 = r0 + 64;
  int g = -1;
  float run = 0.f;
  for (int r = r0; r < r1; ++r) {
    const int bg = batch_lds[r];
    const float v = smem[r * 128 + col];
    if (bg != g) {
      if (g >= 0) atomicAdd(&pooled[g * HD + col], run);
      g = bg;
      run = 0.f;
    }
    if (bg >= 0) run += v;
  }
  if (g >= 0) atomicAdd(&pooled[g * HD + col], run);
}

__global__ __launch_bounds__(256) void k_counts(const int* __restrict__ batch,
                                                float* __restrict__ counts) {
  int i = blockIdx.x * 256 + threadIdx.x;
  if (i < NN) atomicAdd(&counts[batch[i]], 1.f);
}

// ---------------- head: out = relu(pooled/cnt @ l1)@l2 ----------------
__global__ __launch_bounds__(64) void k_head(const float* __restrict__ pooled,
                                             const float* __restrict__ counts,
                                             const float* __restrict__ l1w,
                                             const float* __restrict__ l1b,
                                             const float* __restrict__ l2w,
                                             const float* __restrict__ l2b,
                                             float* __restrict__ out) {
  const int g = blockIdx.x, j = threadIdx.x;
  const float inv = __builtin_amdgcn_rcpf(fmaxf(counts[g], 1.f));
  float acc = l1b[j];
  for (int k = 0; k < HD; ++k)
    acc = fmaf(pooled[g * HD + k] * inv, l1w[k * 64 + j], acc);
  float v = fmaxf(acc, 0.f) * l2w[j];
  v = wave_allsum(v);
  if (j == 0) out[g] = v + l2b[0];
}

extern "C" void kernel_launch(void* const* d_in, const int* in_sizes, int n_in,
                              void* d_out, int out_size, void* d_ws,
                              size_t ws_size, hipStream_t stream) {
  const float* x = (const float*)d_in[0];
  const float* pos = (const float*)d_in[1];
  const int* ei = (const int*)d_in[2];
  const int* batch = (const int*)d_in[3];
  const float* gcn_w = (const float*)d_in[4];
  const float* gcn_b = (const float*)d_in[5];
  const float* pam_w = (const float*)d_in[6];
  const float* pam_b = (const float*)d_in[7];
  const float* pm_w1 = (const float*)d_in[8];
  const float* pm_b1 = (const float*)d_in[9];
  const float* pm_w2 = (const float*)d_in[10];
  const float* pm_b2 = (const float*)d_in[11];
  const float* att_w = (const float*)d_in[12];
  const float* att_b = (const float*)d_in[13];
  const float* fus_w = (const float*)d_in[14];
  const float* fus_b = (const float*)d_in[15];
  const float* l1_w = (const float*)d_in[16];
  const float* l1_b = (const float*)d_in[17];
  const float* l2_w = (const float*)d_in[18];
  const float* l2_b = (const float*)d_in[19];
  float* out = (float*)d_out;

  size_t off = 0;
  auto alloc = [&](size_t elems) {
    void* p = (char*)d_ws + off;
    off += ((elems * 4 + 255) / 256) * 256;
    return p;
  };
  float* xw = (float*)alloc((size_t)NN * HD);
  float* xl = (float*)alloc((size_t)NN * HD);
  float* tb = (float*)alloc((size_t)NN * HD);
  float* Pb = (float*)alloc((size_t)NN * HD);  // becomes localf after k_lgemm
  float* gl = (float*)alloc((size_t)NN * HD);
  float* dinv = (float*)alloc(NN);
  float* ai = (float*)alloc(NN);
  float* aj = (float*)alloc(NN);
  float* pooled = (float*)alloc((size_t)NG * HD);
  float* counts = (float*)alloc(NG);
  int* cnt = (int*)alloc(NN);
  int* cursor = (int*)alloc(NN);
  int* offs = (int*)alloc(NN);
  int* csr_src = (int*)alloc(NE);

  hipMemsetAsync(cnt, 0, NN * 4, stream);
  hipMemsetAsync(cursor, 0, NN * 4, stream);
  hipMemsetAsync(pooled, 0, NG * HD * 4, stream);
  hipMemsetAsync(counts, 0, NG * 4, stream);

  const int nb = (NN + 127) / 128;  // 391
  k_lin<<<dim3(nb, 2), 256, 0, stream>>>(x, gcn_w, pam_w, pam_b, xw, xl);
  k_hist<<<(NE + 255) / 256, 256, 0, stream>>>(ei, cnt);
  k_scan<<<1, 1024, 0, stream>>>(cnt, offs);
  k_scatter<<<(NE + 255) / 256, 256, 0, stream>>>(ei, offs, cursor, csr_src);
  k_dinv<<<(NN + 255) / 256, 256, 0, stream>>>(cnt, dinv);
  k_attpre<<<(NN + 3) / 4, 256, 0, stream>>>(xl, att_w, att_b, ai, aj);
  k_agg<<<(NN + 3) / 4, 256, 0, stream>>>(xw, xl, pos, dinv, csr_src, offs,
                                          cnt, ai, aj, pm_w1, pm_b1, pm_b2,
                                          gcn_b, gl, tb, Pb);
  k_lgemm<<<nb, 256, 0, stream>>>(tb, pm_w2, Pb);
  k_fused<<<nb, 256, 0, stream>>>(gl, Pb, fus_w, fus_b, batch, pooled);
  k_counts<<<(NN + 255) / 256, 256, 0, stream>>>(batch, counts);
  k_head<<<NG, 64, 0, stream>>>(pooled, counts, l1_w, l1_b, l2_w, l2_b, out);
}

// Round 3
// 403.764 us; speedup vs baseline: 2.4208x; 1.3418x over previous
//
#include <hip/hip_runtime.h>
#include <math.h>

#define NN 50000
#define NE 800000
#define HD 128
#define NG 256

typedef unsigned int u32;
typedef unsigned short u16;
typedef __attribute__((ext_vector_type(8))) short bf16x8;
typedef __attribute__((ext_vector_type(4))) float f32x4;

__device__ __forceinline__ float wave_allsum(float v) {
#pragma unroll
  for (int m = 1; m < 64; m <<= 1) v += __shfl_xor(v, m, 64);
  return v;
}
__device__ __forceinline__ float bcastf(float v, int t) {
  return __int_as_float(__builtin_amdgcn_readlane(__float_as_int(v), t));
}
__device__ __forceinline__ u32 f2b_bits(float f) {  // RNE float->bf16 bits
  u32 u = __float_as_uint(f);
  return (u + 0x7fffu + ((u >> 16) & 1u)) >> 16;
}
__device__ __forceinline__ u32 pack2(float lo, float hi) {
  return f2b_bits(lo) | (f2b_bits(hi) << 16);
}
__device__ __forceinline__ float bf2f(u32 bits) {
  return __uint_as_float(bits << 16);
}

// ---------------- x (fp32) -> xb (bf16 packed pairs) ----------------
__global__ __launch_bounds__(256) void k_xcast(const float* __restrict__ x,
                                               u32* __restrict__ xb) {
  int idx = blockIdx.x * 256 + threadIdx.x;  // one u32 = 2 channels
  if (idx < NN * 64) {
    const float2 v = *(const float2*)&x[(size_t)idx * 2];
    xb[idx] = pack2(v.x, v.y);
  }
}

// ------ vi = pam_w@wi, vj = pam_w@wj, consts = {pam_b.wi+att_b, pam_b.wj},
//        bsum = pam_b + pm_b2 ------
__global__ __launch_bounds__(256) void k_prevec(
    const float* __restrict__ pam_w, const float* __restrict__ pam_b,
    const float* __restrict__ att_w, const float* __restrict__ att_b,
    const float* __restrict__ pm_b2, float* __restrict__ vi,
    float* __restrict__ vj, float* __restrict__ consts,
    float* __restrict__ bsum) {
  const int t = threadIdx.x;
  const int k = t & 127;
  const float* w = att_w + (t >> 7) * HD;
  float s = 0.f;
  for (int h = 0; h < HD; ++h) s = fmaf(pam_w[k * HD + h], w[h], s);
  if (t < 128) {
    vi[k] = s;
    bsum[k] = pam_b[k] + pm_b2[k];
  } else {
    vj[k] = s;
  }
  if (t < 64) {
    float p = fmaf(pam_b[t], att_w[t], pam_b[t + 64] * att_w[t + 64]);
    p = wave_allsum(p);
    if (t == 0) consts[0] = p + att_b[0];
  } else if (t < 128) {
    const int l = t - 64;
    float p = fmaf(pam_b[l], att_w[HD + l], pam_b[l + 64] * att_w[HD + 64 + l]);
    p = wave_allsum(p);
    if (l == 0) consts[1] = p;
  }
}

// ---- pack weights to MFMA B-fragment layout: Bp[kb][n][i] = W[kb*8+i][n] ---
__global__ __launch_bounds__(256) void k_wpack(const float* __restrict__ gcn_w,
                                               const float* __restrict__ pam_w,
                                               const float* __restrict__ pm_w2,
                                               const float* __restrict__ fus_w,
                                               u16* __restrict__ Bg,
                                               u16* __restrict__ Bl,
                                               u16* __restrict__ Bf) {
  const int t = blockIdx.x * 256 + threadIdx.x;
  const float* W;
  u16* dst;
  if (t < 2048) {  // gcn_w: K=128 -> 16 kb
    const int kb = t >> 7, n = t & 127;
    W = gcn_w + (size_t)kb * 8 * HD + n;
    dst = Bg + (size_t)t * 8;
  } else if (t < 6144) {  // [pam_w; pm_w2]: K=256 -> 32 kb
    const int u = t - 2048;
    const int kb = u >> 7, n = u & 127;
    W = ((kb < 16) ? (pam_w + (size_t)kb * 8 * HD)
                   : (pm_w2 + (size_t)(kb - 16) * 8 * HD)) + n;
    dst = Bl + (size_t)u * 8;
  } else if (t < 10240) {  // fus_w: K=256 -> 32 kb
    const int u = t - 6144;
    const int kb = u >> 7, n = u & 127;
    W = fus_w + (size_t)kb * 8 * HD + n;
    dst = Bf + (size_t)u * 8;
  } else {
    return;
  }
  union {
    u16 o[8];
    uint4 v;
  } pk;
#pragma unroll
  for (int i = 0; i < 8; ++i) pk.o[i] = (u16)f2b_bits(W[i * HD]);
  *(uint4*)dst = pk.v;
}

// ---------------- CSR build ----------------
__global__ __launch_bounds__(256) void k_hist(const int* __restrict__ ei,
                                              int* __restrict__ cnt) {
  int e = blockIdx.x * 256 + threadIdx.x;
  if (e < NE) atomicAdd(&cnt[ei[NE + e]], 1);
}

__global__ __launch_bounds__(1024) void k_scan(const int* __restrict__ cnt,
                                               int* __restrict__ offs) {
  __shared__ int sums[1024];
  const int t = threadIdx.x;
  const int chunk = (NN + 1023) >> 10;
  const int b = t * chunk;
  const int e = min(b + chunk, NN);
  int s = 0;
  for (int i = b; i < e; ++i) s += cnt[i];
  sums[t] = s;
  __syncthreads();
  for (int d = 1; d < 1024; d <<= 1) {
    int add = (t >= d) ? sums[t - d] : 0;
    __syncthreads();
    sums[t] += add;
    __syncthreads();
  }
  int pre = (t > 0) ? sums[t - 1] : 0;
  for (int i = b; i < e; ++i) {
    offs[i] = pre;
    pre += cnt[i];
  }
}

__global__ __launch_bounds__(256) void k_scatter(const int* __restrict__ ei,
                                                 const int* __restrict__ offs,
                                                 int* __restrict__ cursor,
                                                 int* __restrict__ csr_src) {
  int e = blockIdx.x * 256 + threadIdx.x;
  if (e < NE) {
    int d = ei[NE + e];
    int slot = atomicAdd(&cursor[d], 1);
    csr_src[offs[d] + slot] = ei[e];
  }
}

__global__ __launch_bounds__(256) void k_dinv(const int* __restrict__ cnt,
                                              float* __restrict__ dinv) {
  int i = blockIdx.x * 256 + threadIdx.x;
  if (i < NN) dinv[i] = __builtin_amdgcn_rsqf((float)cnt[i] + 1.0f);
}

// -------- per-node attention dots straight from x: ai = x.vi+c0, aj = x.vj+c1
__global__ __launch_bounds__(256) void k_attpre(const float* __restrict__ x,
                                                const float* __restrict__ vi,
                                                const float* __restrict__ vj,
                                                const float* __restrict__ consts,
                                                float* __restrict__ ai,
                                                float* __restrict__ aj) {
  const int wave = threadIdx.x >> 6, lane = threadIdx.x & 63;
  const int i = blockIdx.x * 4 + wave;
  if (i >= NN) return;
  const float2 v = *(const float2*)&x[(size_t)i * HD + lane * 2];
  const float2 a = *(const float2*)&vi[lane * 2];
  const float2 b = *(const float2*)&vj[lane * 2];
  float si = wave_allsum(fmaf(v.x, a.x, v.y * a.y));
  float sj = wave_allsum(fmaf(v.x, b.x, v.y * b.y));
  if (lane == 0) {
    ai[i] = si + consts[0];
    aj[i] = sj + consts[1];
  }
}

// ---------------- per-node edge aggregation (1 wave / node) ----------------
// Zg_i = sum dinv_s*x_s + dinv_i*x_i ; Xa_i = sum att*x_s ; t_i = sum att*g(d)
// sa_i = sum att.  Outputs bf16 (ZG [N,128]; XT = [Xa | t] [N,256]).
__global__ __launch_bounds__(256) void k_agg(
    const u32* __restrict__ xb, const float* __restrict__ pos,
    const float* __restrict__ dinv, const int* __restrict__ csr_src,
    const int* __restrict__ offs, const int* __restrict__ cnt,
    const float* __restrict__ ai_arr, const float* __restrict__ aj_arr,
    const float* __restrict__ pm_w1, const float* __restrict__ pm_b1,
    u32* __restrict__ ZG, u32* __restrict__ XT, float* __restrict__ sa_out) {
  const int wave = threadIdx.x >> 6, lane = threadIdx.x & 63;
  const int i = blockIdx.x * 4 + wave;
  if (i >= NN) return;
  const int c0 = lane * 2;

  const float2 w1x = *(const float2*)&pm_w1[c0];
  const float2 w1y = *(const float2*)&pm_w1[HD + c0];
  const float2 w1z = *(const float2*)&pm_w1[2 * HD + c0];
  const float2 b1 = *(const float2*)&pm_b1[c0];
  const float ai = ai_arr[i];
  const float pix = pos[i * 3], piy = pos[i * 3 + 1], piz = pos[i * 3 + 2];
  const float di = dinv[i];

  float zg0 = 0.f, zg1 = 0.f, xa0 = 0.f, xa1 = 0.f, t0 = 0.f, t1 = 0.f,
        sa = 0.f;
  const int b = offs[i], e = b + cnt[i];
  for (int base = b; base < e; base += 64) {
    const int mm = min(64, e - base);
    const int sk = csr_src[base + ((lane < mm) ? lane : 0)];
    float attk = ai + aj_arr[sk];
    attk = __builtin_amdgcn_rcpf(1.f + __expf(-attk));
    const float dsk = dinv[sk];
    const float dxk = pix - pos[sk * 3];
    const float dyk = piy - pos[sk * 3 + 1];
    const float dzk = piz - pos[sk * 3 + 2];
    for (int t = 0; t < mm; ++t) {
      const int s = __builtin_amdgcn_readlane(sk, t);
      const float att = bcastf(attk, t);
      const float ds = bcastf(dsk, t);
      const float dx = bcastf(dxk, t);
      const float dy = bcastf(dyk, t);
      const float dz = bcastf(dzk, t);
      const u32 xr = xb[(size_t)s * 64 + lane];
      const float xj0 = bf2f(xr & 0xffffu), xj1 = bf2f(xr >> 16);
      zg0 = fmaf(ds, xj0, zg0);
      zg1 = fmaf(ds, xj1, zg1);
      xa0 = fmaf(att, xj0, xa0);
      xa1 = fmaf(att, xj1, xa1);
      const float g0 =
          fmaxf(fmaf(dz, w1z.x, fmaf(dy, w1y.x, fmaf(dx, w1x.x, b1.x))), 0.f);
      const float g1 =
          fmaxf(fmaf(dz, w1z.y, fmaf(dy, w1y.y, fmaf(dx, w1x.y, b1.y))), 0.f);
      t0 = fmaf(att, g0, t0);
      t1 = fmaf(att, g1, t1);
      sa += att;
    }
  }
  const u32 xi = xb[(size_t)i * 64 + lane];
  zg0 = fmaf(di, bf2f(xi & 0xffffu), zg0);
  zg1 = fmaf(di, bf2f(xi >> 16), zg1);

  ZG[(size_t)i * 64 + lane] = pack2(zg0, zg1);
  XT[(size_t)i * 128 + lane] = pack2(xa0, xa1);
  XT[(size_t)i * 128 + 64 + lane] = pack2(t0, t1);
  if (lane == 0) sa_out[i] = sa;
}

// ---------------- LDS-free MFMA bf16 GEMM core ----------------
// Block = 256 thr = 4 waves; tile 128 rows x 128 cols; wave w = rows w*32..+31.
// A [rows][K] bf16 row-major; Bp fragment-major [K/8][128][8].
__device__ __forceinline__ void mfma_loop(const u16* __restrict__ A, int K,
                                          const u16* __restrict__ Bp,
                                          f32x4 acc[2][8], int n0) {
  const int lane = threadIdx.x & 63;
  const int wid = threadIdx.x >> 6;
  const int m = lane & 15, g = lane >> 4;
  const int rA0 = min(n0 + wid * 32 + m, NN - 1);
  const int rA1 = min(n0 + wid * 32 + 16 + m, NN - 1);
  const u16* pa0 = A + (size_t)rA0 * K + g * 8;
  const u16* pa1 = A + (size_t)rA1 * K + g * 8;
  const u16* pb0 = Bp + ((size_t)g * HD + m) * 8;
  for (int k0 = 0; k0 < K; k0 += 32) {
    const bf16x8 a0 = *(const bf16x8*)(pa0 + k0);
    const bf16x8 a1 = *(const bf16x8*)(pa1 + k0);
    const u16* pb = pb0 + (size_t)(k0 >> 3) * HD * 8;
#pragma unroll
    for (int cf = 0; cf < 8; ++cf) {
      const bf16x8 b = *(const bf16x8*)(pb + cf * 16 * 8);
      acc[0][cf] =
          __builtin_amdgcn_mfma_f32_16x16x32_bf16(a0, b, acc[0][cf], 0, 0, 0);
      acc[1][cf] =
          __builtin_amdgcn_mfma_f32_16x16x32_bf16(a1, b, acc[1][cf], 0, 0, 0);
    }
  }
}

// G1: gl = relu(dinv_i*(ZG@gcn_w) + gcn_b) -> GLloc[:, 0:128]
__global__ __launch_bounds__(256) void k_gemm_gcn(
    const u16* __restrict__ ZG, const u16* __restrict__ Bg,
    const float* __restrict__ dinv, const float* __restrict__ gcn_b,
    u16* __restrict__ GLloc) {
  f32x4 acc[2][8] = {};
  const int n0 = blockIdx.x * 128;
  mfma_loop(ZG, 128, Bg, acc, n0);
  const int lane = threadIdx.x & 63, wid = threadIdx.x >> 6;
  const int m = lane & 15, g = lane >> 4;
  float bv[8];
#pragma unroll
  for (int cf = 0; cf < 8; ++cf) bv[cf] = gcn_b[cf * 16 + m];
#pragma unroll
  for (int rf = 0; rf < 2; ++rf)
#pragma unroll
    for (int j = 0; j < 4; ++j) {
      const int row = n0 + wid * 32 + rf * 16 + g * 4 + j;
      if (row < NN) {
        const float dv = dinv[row];
#pragma unroll
        for (int cf = 0; cf < 8; ++cf) {
          const float v = fmaxf(fmaf(dv, acc[rf][cf][j], bv[cf]), 0.f);
          GLloc[(size_t)row * 256 + cf * 16 + m] = (u16)f2b_bits(v);
        }
      }
    }
}

// G2: local = relu(XT@[pam_w;pm_w2] + sa_i*bsum) -> GLloc[:, 128:256]
__global__ __launch_bounds__(256) void k_gemm_loc(
    const u16* __restrict__ XT, const u16* __restrict__ Bl,
    const float* __restrict__ sa, const float* __restrict__ bsum,
    u16* __restrict__ GLloc) {
  f32x4 acc[2][8] = {};
  const int n0 = blockIdx.x * 128;
  mfma_loop(XT, 256, Bl, acc, n0);
  const int lane = threadIdx.x & 63, wid = threadIdx.x >> 6;
  const int m = lane & 15, g = lane >> 4;
  float bv[8];
#pragma unroll
  for (int cf = 0; cf < 8; ++cf) bv[cf] = bsum[cf * 16 + m];
#pragma unroll
  for (int rf = 0; rf < 2; ++rf)
#pragma unroll
    for (int j = 0; j < 4; ++j) {
      const int row = n0 + wid * 32 + rf * 16 + g * 4 + j;
      if (row < NN) {
        const float sv = sa[row];
#pragma unroll
        for (int cf = 0; cf < 8; ++cf) {
          const float v = fmaxf(fmaf(sv, bv[cf], acc[rf][cf][j]), 0.f);
          GLloc[(size_t)row * 256 + 128 + cf * 16 + m] = (u16)f2b_bits(v);
        }
      }
    }
}

// G3: fused = relu(GLloc@fus_w + fus_b); segment-pool into pooled
__global__ __launch_bounds__(256) void k_gemm_fus(
    const u16* __restrict__ GLloc, const u16* __restrict__ Bf,
    const float* __restrict__ fus_b, const int* __restrict__ batch,
    float* __restrict__ pooled) {
  __shared__ float smem[128 * 128];
  __shared__ int batch_lds[128];
  f32x4 acc[2][8] = {};
  const int n0 = blockIdx.x * 128;
  mfma_loop(GLloc, 256, Bf, acc, n0);
  const int t = threadIdx.x;
  const int lane = t & 63, wid = t >> 6;
  const int m = lane & 15, g = lane >> 4;
  float bv[8];
#pragma unroll
  for (int cf = 0; cf < 8; ++cf) bv[cf] = fus_b[cf * 16 + m];
#pragma unroll
  for (int rf = 0; rf < 2; ++rf)
#pragma unroll
    for (int j = 0; j < 4; ++j) {
      const int rl = wid * 32 + rf * 16 + g * 4 + j;
#pragma unroll
      for (int cf = 0; cf < 8; ++cf)
        smem[rl * 128 + cf * 16 + m] = fmaxf(acc[rf][cf][j] + bv[cf], 0.f);
    }
  if (t < 128) batch_lds[t] = (n0 + t < NN) ? batch[n0 + t] : -1;
  __syncthreads();

  const int col = t & 127;
  const int r0 = (t >> 7) * 64, r1 = r0 + 64;
  int seg = -1;
  float run = 0.f;
  for (int r = r0; r < r1; ++r) {
    const int bg = batch_lds[r];
    const float v = smem[r * 128 + col];
    if (bg != seg) {
      if (seg >= 0) atomicAdd(&pooled[seg * HD + col], run);
      seg = bg;
      run = 0.f;
    }
    if (bg >= 0) run += v;
  }
  if (seg >= 0) atomicAdd(&pooled[seg * HD + col], run);
}

__global__ __launch_bounds__(256) void k_counts(const int* __restrict__ batch,
                                                float* __restrict__ counts) {
  int i = blockIdx.x * 256 + threadIdx.x;
  if (i < NN) atomicAdd(&counts[batch[i]], 1.f);
}

// ---------------- head: out = relu(pooled/cnt @ l1)@l2 ----------------
__global__ __launch_bounds__(64) void k_head(const float* __restrict__ pooled,
                                             const float* __restrict__ counts,
                                             const float* __restrict__ l1w,
                                             const float* __restrict__ l1b,
                                             const float* __restrict__ l2w,
                                             const float* __restrict__ l2b,
                                             float* __restrict__ out) {
  const int g = blockIdx.x, j = threadIdx.x;
  const float inv = __builtin_amdgcn_rcpf(fmaxf(counts[g], 1.f));
  float acc = l1b[j];
  for (int k = 0; k < HD; ++k)
    acc = fmaf(pooled[g * HD + k] * inv, l1w[k * 64 + j], acc);
  float v = fmaxf(acc, 0.f) * l2w[j];
  v = wave_allsum(v);
  if (j == 0) out[g] = v + l2b[0];
}

extern "C" void kernel_launch(void* const* d_in, const int* in_sizes, int n_in,
                              void* d_out, int out_size, void* d_ws,
                              size_t ws_size, hipStream_t stream) {
  const float* x = (const float*)d_in[0];
  const float* pos = (const float*)d_in[1];
  const int* ei = (const int*)d_in[2];
  const int* batch = (const int*)d_in[3];
  const float* gcn_w = (const float*)d_in[4];
  const float* gcn_b = (const float*)d_in[5];
  const float* pam_w = (const float*)d_in[6];
  const float* pam_b = (const float*)d_in[7];
  const float* pm_w1 = (const float*)d_in[8];
  const float* pm_b1 = (const float*)d_in[9];
  const float* pm_w2 = (const float*)d_in[10];
  const float* pm_b2 = (const float*)d_in[11];
  const float* att_w = (const float*)d_in[12];
  const float* att_b = (const float*)d_in[13];
  const float* fus_w = (const float*)d_in[14];
  const float* fus_b = (const float*)d_in[15];
  const float* l1_w = (const float*)d_in[16];
  const float* l1_b = (const float*)d_in[17];
  const float* l2_w = (const float*)d_in[18];
  const float* l2_b = (const float*)d_in[19];
  float* out = (float*)d_out;

  size_t off = 0;
  auto alloc = [&](size_t bytes) {
    void* p = (char*)d_ws + off;
    off += (bytes + 255) & ~size_t(255);
    return p;
  };
  u32* xb = (u32*)alloc((size_t)NN * 64 * 4);        // bf16 x, packed pairs
  u32* ZG = (u32*)alloc((size_t)NN * 64 * 4);        // bf16 [N,128]
  u32* XT = (u32*)alloc((size_t)NN * 128 * 4);       // bf16 [N,256] = [Xa|t]
  u16* GLloc = (u16*)alloc((size_t)NN * 256 * 2);    // bf16 [N,256] = [gl|loc]
  float* sa = (float*)alloc((size_t)NN * 4);
  float* dinv = (float*)alloc((size_t)NN * 4);
  float* ai = (float*)alloc((size_t)NN * 4);
  float* aj = (float*)alloc((size_t)NN * 4);
  float* pooled = (float*)alloc((size_t)NG * HD * 4);
  float* counts = (float*)alloc((size_t)NG * 4);
  int* cnt = (int*)alloc((size_t)NN * 4);
  int* cursor = (int*)alloc((size_t)NN * 4);
  int* offs = (int*)alloc((size_t)NN * 4);
  int* csr_src = (int*)alloc((size_t)NE * 4);
  u16* Bg = (u16*)alloc((size_t)16 * 128 * 8 * 2);
  u16* Bl = (u16*)alloc((size_t)32 * 128 * 8 * 2);
  u16* Bf = (u16*)alloc((size_t)32 * 128 * 8 * 2);
  float* vi = (float*)alloc(128 * 4);
  float* vj = (float*)alloc(128 * 4);
  float* consts = (float*)alloc(2 * 4);
  float* bsum = (float*)alloc(128 * 4);

  hipMemsetAsync(cnt, 0, NN * 4, stream);
  hipMemsetAsync(cursor, 0, NN * 4, stream);
  hipMemsetAsync(pooled, 0, NG * HD * 4, stream);
  hipMemsetAsync(counts, 0, NG * 4, stream);

  k_xcast<<<(NN * 64 + 255) / 256, 256, 0, stream>>>(x, xb);
  k_prevec<<<1, 256, 0, stream>>>(pam_w, pam_b, att_w, att_b, pm_b2, vi, vj,
                                  consts, bsum);
  k_wpack<<<40, 256, 0, stream>>>(gcn_w, pam_w, pm_w2, fus_w, Bg, Bl, Bf);
  k_hist<<<(NE + 255) / 256, 256, 0, stream>>>(ei, cnt);
  k_scan<<<1, 1024, 0, stream>>>(cnt, offs);
  k_scatter<<<(NE + 255) / 256, 256, 0, stream>>>(ei, offs, cursor, csr_src);
  k_dinv<<<(NN + 255) / 256, 256, 0, stream>>>(cnt, dinv);
  k_attpre<<<(NN + 3) / 4, 256, 0, stream>>>(x, vi, vj, consts, ai, aj);
  k_agg<<<(NN + 3) / 4, 256, 0, stream>>>(xb, pos, dinv, csr_src, offs, cnt,
                                          ai, aj, pm_w1, pm_b1, ZG, XT, sa);
  const int nb = (NN + 127) / 128;  // 391
  k_gemm_gcn<<<nb, 256, 0, stream>>>((const u16*)ZG, Bg, dinv, gcn_b, GLloc);
  k_gemm_loc<<<nb, 256, 0, stream>>>((const u16*)XT, Bl, sa, bsum, GLloc);
  k_gemm_fus<<<nb, 256, 0, stream>>>(GLloc, Bf, fus_b, batch, pooled);
  k_counts<<<(NN + 255) / 256, 256, 0, stream>>>(batch, counts);
  k_head<<<NG, 64, 0, stream>>>(pooled, counts, l1_w, l1_b, l2_w, l2_b, out);
}

// Round 4
// 253.685 us; speedup vs baseline: 3.8529x; 1.5916x over previous
//
#include <hip/hip_runtime.h>
#include <math.h>

#define NN 50000
#define NE 800000
#define HD 128
#define NG 256
#define SCAN_B 196  // ceil(NN/256)

typedef unsigned int u32;
typedef unsigned short u16;
typedef __attribute__((ext_vector_type(8))) short bf16x8;
typedef __attribute__((ext_vector_type(4))) float f32x4;

__device__ __forceinline__ float wave_allsum(float v) {
#pragma unroll
  for (int m = 1; m < 64; m <<= 1) v += __shfl_xor(v, m, 64);
  return v;
}
__device__ __forceinline__ int wave_allsum_i(int v) {
#pragma unroll
  for (int m = 1; m < 64; m <<= 1) v += __shfl_xor(v, m, 64);
  return v;
}
__device__ __forceinline__ float bcastf(float v, int t) {
  return __int_as_float(__builtin_amdgcn_readlane(__float_as_int(v), t));
}
__device__ __forceinline__ u32 f2b_bits(float f) {  // RNE float->bf16 bits
  u32 u = __float_as_uint(f);
  return (u + 0x7fffu + ((u >> 16) & 1u)) >> 16;
}
__device__ __forceinline__ u32 pack2(float lo, float hi) {
  return f2b_bits(lo) | (f2b_bits(hi) << 16);
}
__device__ __forceinline__ float bf2f(u32 bits) {
  return __uint_as_float(bits << 16);
}

// ---- x (fp32) -> xb (bf16 pairs) + per-node attention dots (fused) ----
__global__ __launch_bounds__(256) void k_xcast(
    const float* __restrict__ x, const float* __restrict__ vi,
    const float* __restrict__ vj, const float* __restrict__ consts,
    u32* __restrict__ xb, float* __restrict__ ai, float* __restrict__ aj) {
  const int wave = threadIdx.x >> 6, lane = threadIdx.x & 63;
  const int i = blockIdx.x * 4 + wave;
  if (i >= NN) return;
  const float2 v = *(const float2*)&x[(size_t)i * HD + lane * 2];
  xb[(size_t)i * 64 + lane] = pack2(v.x, v.y);
  const float2 a = *(const float2*)&vi[lane * 2];
  const float2 b = *(const float2*)&vj[lane * 2];
  float si = wave_allsum(fmaf(v.x, a.x, v.y * a.y));
  float sj = wave_allsum(fmaf(v.x, b.x, v.y * b.y));
  if (lane == 0) {
    ai[i] = si + consts[0];
    aj[i] = sj + consts[1];
  }
}

// ---- pack weights to MFMA B-fragment layout (blocks 0..39); block 40 =
//      prevec: vi = pam_w@wi, vj = pam_w@wj, consts, bsum = pam_b + pm_b2 ----
__global__ __launch_bounds__(256) void k_wpack(
    const float* __restrict__ gcn_w, const float* __restrict__ pam_w,
    const float* __restrict__ pm_w2, const float* __restrict__ fus_w,
    const float* __restrict__ pam_b, const float* __restrict__ att_w,
    const float* __restrict__ att_b, const float* __restrict__ pm_b2,
    u16* __restrict__ Bg, u16* __restrict__ Bl, u16* __restrict__ Bf,
    float* __restrict__ vi, float* __restrict__ vj,
    float* __restrict__ consts, float* __restrict__ bsum) {
  if (blockIdx.x == 40) {  // prevec
    const int t = threadIdx.x;
    const int k = t & 127;
    const float* w = att_w + (t >> 7) * HD;
    float s = 0.f;
    for (int h = 0; h < HD; ++h) s = fmaf(pam_w[k * HD + h], w[h], s);
    if (t < 128) {
      vi[k] = s;
      bsum[k] = pam_b[k] + pm_b2[k];
    } else {
      vj[k] = s;
    }
    if (t < 64) {
      float p = fmaf(pam_b[t], att_w[t], pam_b[t + 64] * att_w[t + 64]);
      p = wave_allsum(p);
      if (t == 0) consts[0] = p + att_b[0];
    } else if (t < 128) {
      const int l = t - 64;
      float p =
          fmaf(pam_b[l], att_w[HD + l], pam_b[l + 64] * att_w[HD + 64 + l]);
      p = wave_allsum(p);
      if (l == 0) consts[1] = p;
    }
    return;
  }
  const int t = blockIdx.x * 256 + threadIdx.x;
  const float* W;
  u16* dst;
  if (t < 2048) {  // gcn_w: K=128 -> 16 kb
    const int kb = t >> 7, n = t & 127;
    W = gcn_w + (size_t)kb * 8 * HD + n;
    dst = Bg + (size_t)t * 8;
  } else if (t < 6144) {  // [pam_w; pm_w2]: K=256 -> 32 kb
    const int u = t - 2048;
    const int kb = u >> 7, n = u & 127;
    W = ((kb < 16) ? (pam_w + (size_t)kb * 8 * HD)
                   : (pm_w2 + (size_t)(kb - 16) * 8 * HD)) +
        n;
    dst = Bl + (size_t)u * 8;
  } else {  // fus_w: K=256 -> 32 kb
    const int u = t - 6144;
    const int kb = u >> 7, n = u & 127;
    W = fus_w + (size_t)kb * 8 * HD + n;
    dst = Bf + (size_t)u * 8;
  }
  union {
    u16 o[8];
    uint4 v;
  } pk;
#pragma unroll
  for (int i = 0; i < 8; ++i) pk.o[i] = (u16)f2b_bits(W[i * HD]);
  *(uint4*)dst = pk.v;
}

// ---------------- CSR build ----------------
__global__ __launch_bounds__(256) void k_hist(const int* __restrict__ ei,
                                              int* __restrict__ cnt) {
  int e = blockIdx.x * 256 + threadIdx.x;
  if (e < NE) atomicAdd(&cnt[ei[NE + e]], 1);
}

// hierarchical scan: per-block sums -> scan of sums -> per-block offsets+dinv
__global__ __launch_bounds__(256) void k_scan1(const int* __restrict__ cnt,
                                               int* __restrict__ bsum) {
  const int i = blockIdx.x * 256 + threadIdx.x;
  int v = (i < NN) ? cnt[i] : 0;
  v = wave_allsum_i(v);
  __shared__ int s[4];
  if ((threadIdx.x & 63) == 0) s[threadIdx.x >> 6] = v;
  __syncthreads();
  if (threadIdx.x == 0) bsum[blockIdx.x] = s[0] + s[1] + s[2] + s[3];
}

__global__ __launch_bounds__(256) void k_scan2(int* __restrict__ bsum) {
  __shared__ int s[256];
  const int t = threadIdx.x;
  const int v = (t < SCAN_B) ? bsum[t] : 0;
  s[t] = v;
  __syncthreads();
  for (int d = 1; d < 256; d <<= 1) {
    int add = (t >= d) ? s[t - d] : 0;
    __syncthreads();
    s[t] += add;
    __syncthreads();
  }
  if (t < SCAN_B) bsum[t] = s[t] - v;  // exclusive
}

__global__ __launch_bounds__(256) void k_scan3(const int* __restrict__ cnt,
                                               const int* __restrict__ bsum,
                                               int* __restrict__ offs,
                                               float* __restrict__ dinv) {
  const int t = threadIdx.x;
  const int i = blockIdx.x * 256 + t;
  const int v = (i < NN) ? cnt[i] : 0;
  __shared__ int s[256];
  s[t] = v;
  __syncthreads();
  for (int d = 1; d < 256; d <<= 1) {
    int add = (t >= d) ? s[t - d] : 0;
    __syncthreads();
    s[t] += add;
    __syncthreads();
  }
  if (i < NN) {
    offs[i] = bsum[blockIdx.x] + s[t] - v;
    dinv[i] = __builtin_amdgcn_rsqf((float)v + 1.0f);
  }
}

__global__ __launch_bounds__(256) void k_scatter(const int* __restrict__ ei,
                                                 const int* __restrict__ offs,
                                                 int* __restrict__ cursor,
                                                 int* __restrict__ csr_src) {
  int e = blockIdx.x * 256 + threadIdx.x;
  if (e < NE) {
    int d = ei[NE + e];
    int slot = atomicAdd(&cursor[d], 1);
    csr_src[offs[d] + slot] = ei[e];
  }
}

// ---- graph sizes via binary search over sorted batch (no atomics) ----
__global__ __launch_bounds__(256) void k_gcounts(const int* __restrict__ batch,
                                                 float* __restrict__ counts) {
  const int g = threadIdx.x;
  int lo = 0, hi = NN;
  while (lo < hi) {
    const int mid = (lo + hi) >> 1;
    if (batch[mid] < g) lo = mid + 1; else hi = mid;
  }
  const int b0 = lo;
  hi = NN;
  while (lo < hi) {
    const int mid = (lo + hi) >> 1;
    if (batch[mid] <= g) lo = mid + 1; else hi = mid;
  }
  counts[g] = (float)(lo - b0);
}

// ---------------- per-node edge aggregation (1 wave / node) ----------------
__global__ __launch_bounds__(256) void k_agg(
    const u32* __restrict__ xb, const float* __restrict__ pos,
    const float* __restrict__ dinv, const int* __restrict__ csr_src,
    const int* __restrict__ offs, const int* __restrict__ cnt,
    const float* __restrict__ ai_arr, const float* __restrict__ aj_arr,
    const float* __restrict__ pm_w1, const float* __restrict__ pm_b1,
    u32* __restrict__ ZG, u32* __restrict__ XT, float* __restrict__ sa_out) {
  const int wave = threadIdx.x >> 6, lane = threadIdx.x & 63;
  const int i = blockIdx.x * 4 + wave;
  if (i >= NN) return;
  const int c0 = lane * 2;

  const float2 w1x = *(const float2*)&pm_w1[c0];
  const float2 w1y = *(const float2*)&pm_w1[HD + c0];
  const float2 w1z = *(const float2*)&pm_w1[2 * HD + c0];
  const float2 b1 = *(const float2*)&pm_b1[c0];
  const float ai = ai_arr[i];
  const float pix = pos[i * 3], piy = pos[i * 3 + 1], piz = pos[i * 3 + 2];
  const float di = dinv[i];

  float zg0 = 0.f, zg1 = 0.f, xa0 = 0.f, xa1 = 0.f, t0 = 0.f, t1 = 0.f,
        sa = 0.f;
  const int b = offs[i], e = b + cnt[i];
  for (int base = b; base < e; base += 64) {
    const int mm = min(64, e - base);
    const int sk = csr_src[base + ((lane < mm) ? lane : 0)];
    float attk = ai + aj_arr[sk];
    attk = __builtin_amdgcn_rcpf(1.f + __expf(-attk));
    const float dsk = dinv[sk];
    const float dxk = pix - pos[sk * 3];
    const float dyk = piy - pos[sk * 3 + 1];
    const float dzk = piz - pos[sk * 3 + 2];
    for (int t = 0; t < mm; ++t) {
      const int s = __builtin_amdgcn_readlane(sk, t);
      const float att = bcastf(attk, t);
      const float ds = bcastf(dsk, t);
      const float dx = bcastf(dxk, t);
      const float dy = bcastf(dyk, t);
      const float dz = bcastf(dzk, t);
      const u32 xr = xb[(size_t)s * 64 + lane];
      const float xj0 = bf2f(xr & 0xffffu), xj1 = bf2f(xr >> 16);
      zg0 = fmaf(ds, xj0, zg0);
      zg1 = fmaf(ds, xj1, zg1);
      xa0 = fmaf(att, xj0, xa0);
      xa1 = fmaf(att, xj1, xa1);
      const float g0 =
          fmaxf(fmaf(dz, w1z.x, fmaf(dy, w1y.x, fmaf(dx, w1x.x, b1.x))), 0.f);
      const float g1 =
          fmaxf(fmaf(dz, w1z.y, fmaf(dy, w1y.y, fmaf(dx, w1x.y, b1.y))), 0.f);
      t0 = fmaf(att, g0, t0);
      t1 = fmaf(att, g1, t1);
      sa += att;
    }
  }
  const u32 xi = xb[(size_t)i * 64 + lane];
  zg0 = fmaf(di, bf2f(xi & 0xffffu), zg0);
  zg1 = fmaf(di, bf2f(xi >> 16), zg1);

  ZG[(size_t)i * 64 + lane] = pack2(zg0, zg1);
  XT[(size_t)i * 128 + lane] = pack2(xa0, xa1);
  XT[(size_t)i * 128 + 64 + lane] = pack2(t0, t1);
  if (lane == 0) sa_out[i] = sa;
}

// ---------------- LDS-free MFMA bf16 GEMM core ----------------
__device__ __forceinline__ void mfma_loop(const u16* __restrict__ A, int K,
                                          const u16* __restrict__ Bp,
                                          f32x4 acc[2][8], int n0) {
  const int lane = threadIdx.x & 63;
  const int wid = threadIdx.x >> 6;
  const int m = lane & 15, g = lane >> 4;
  const int rA0 = min(n0 + wid * 32 + m, NN - 1);
  const int rA1 = min(n0 + wid * 32 + 16 + m, NN - 1);
  const u16* pa0 = A + (size_t)rA0 * K + g * 8;
  const u16* pa1 = A + (size_t)rA1 * K + g * 8;
  const u16* pb0 = Bp + ((size_t)g * HD + m) * 8;
  for (int k0 = 0; k0 < K; k0 += 32) {
    const bf16x8 a0 = *(const bf16x8*)(pa0 + k0);
    const bf16x8 a1 = *(const bf16x8*)(pa1 + k0);
    const u16* pb = pb0 + (size_t)(k0 >> 3) * HD * 8;
#pragma unroll
    for (int cf = 0; cf < 8; ++cf) {
      const bf16x8 b = *(const bf16x8*)(pb + cf * 16 * 8);
      acc[0][cf] =
          __builtin_amdgcn_mfma_f32_16x16x32_bf16(a0, b, acc[0][cf], 0, 0, 0);
      acc[1][cf] =
          __builtin_amdgcn_mfma_f32_16x16x32_bf16(a1, b, acc[1][cf], 0, 0, 0);
    }
  }
}

// G1: gl = relu(dinv_i*(ZG@gcn_w) + gcn_b) -> GLloc[:, 0:128]
__global__ __launch_bounds__(256) void k_gemm_gcn(
    const u16* __restrict__ ZG, const u16* __restrict__ Bg,
    const float* __restrict__ dinv, const float* __restrict__ gcn_b,
    u16* __restrict__ GLloc) {
  f32x4 acc[2][8] = {};
  const int n0 = blockIdx.x * 128;
  mfma_loop(ZG, 128, Bg, acc, n0);
  const int lane = threadIdx.x & 63, wid = threadIdx.x >> 6;
  const int m = lane & 15, g = lane >> 4;
  float bv[8];
#pragma unroll
  for (int cf = 0; cf < 8; ++cf) bv[cf] = gcn_b[cf * 16 + m];
#pragma unroll
  for (int rf = 0; rf < 2; ++rf)
#pragma unroll
    for (int j = 0; j < 4; ++j) {
      const int row = n0 + wid * 32 + rf * 16 + g * 4 + j;
      if (row < NN) {
        const float dv = dinv[row];
#pragma unroll
        for (int cf = 0; cf < 8; ++cf) {
          const float v = fmaxf(fmaf(dv, acc[rf][cf][j], bv[cf]), 0.f);
          GLloc[(size_t)row * 256 + cf * 16 + m] = (u16)f2b_bits(v);
        }
      }
    }
}

// G2: local = relu(XT@[pam_w;pm_w2] + sa_i*bsum) -> GLloc[:, 128:256]
__global__ __launch_bounds__(256) void k_gemm_loc(
    const u16* __restrict__ XT, const u16* __restrict__ Bl,
    const float* __restrict__ sa, const float* __restrict__ bsum,
    u16* __restrict__ GLloc) {
  f32x4 acc[2][8] = {};
  const int n0 = blockIdx.x * 128;
  mfma_loop(XT, 256, Bl, acc, n0);
  const int lane = threadIdx.x & 63, wid = threadIdx.x >> 6;
  const int m = lane & 15, g = lane >> 4;
  float bv[8];
#pragma unroll
  for (int cf = 0; cf < 8; ++cf) bv[cf] = bsum[cf * 16 + m];
#pragma unroll
  for (int rf = 0; rf < 2; ++rf)
#pragma unroll
    for (int j = 0; j < 4; ++j) {
      const int row = n0 + wid * 32 + rf * 16 + g * 4 + j;
      if (row < NN) {
        const float sv = sa[row];
#pragma unroll
        for (int cf = 0; cf < 8; ++cf) {
          const float v = fmaxf(fmaf(sv, bv[cf], acc[rf][cf][j]), 0.f);
          GLloc[(size_t)row * 256 + 128 + cf * 16 + m] = (u16)f2b_bits(v);
        }
      }
    }
}

// G3: fused = relu(GLloc@fus_w + fus_b); segment-pool into pooled
__global__ __launch_bounds__(256) void k_gemm_fus(
    const u16* __restrict__ GLloc, const u16* __restrict__ Bf,
    const float* __restrict__ fus_b, const int* __restrict__ batch,
    float* __restrict__ pooled) {
  __shared__ float smem[128 * 128];
  __shared__ int batch_lds[128];
  f32x4 acc[2][8] = {};
  const int n0 = blockIdx.x * 128;
  mfma_loop(GLloc, 256, Bf, acc, n0);
  const int t = threadIdx.x;
  const int lane = t & 63, wid = t >> 6;
  const int m = lane & 15, g = lane >> 4;
  float bv[8];
#pragma unroll
  for (int cf = 0; cf < 8; ++cf) bv[cf] = fus_b[cf * 16 + m];
#pragma unroll
  for (int rf = 0; rf < 2; ++rf)
#pragma unroll
    for (int j = 0; j < 4; ++j) {
      const int rl = wid * 32 + rf * 16 + g * 4 + j;
#pragma unroll
      for (int cf = 0; cf < 8; ++cf)
        smem[rl * 128 + cf * 16 + m] = fmaxf(acc[rf][cf][j] + bv[cf], 0.f);
    }
  if (t < 128) batch_lds[t] = (n0 + t < NN) ? batch[n0 + t] : -1;
  __syncthreads();

  const int col = t & 127;
  const int r0 = (t >> 7) * 64, r1 = r0 + 64;
  int seg = -1;
  float run = 0.f;
  for (int r = r0; r < r1; ++r) {
    const int bg = batch_lds[r];
    const float v = smem[r * 128 + col];
    if (bg != seg) {
      if (seg >= 0) atomicAdd(&pooled[seg * HD + col], run);
      seg = bg;
      run = 0.f;
    }
    if (bg >= 0) run += v;
  }
  if (seg >= 0) atomicAdd(&pooled[seg * HD + col], run);
}

// ---------------- head: out = relu(pooled/cnt @ l1)@l2 ----------------
__global__ __launch_bounds__(64) void k_head(const float* __restrict__ pooled,
                                             const float* __restrict__ counts,
                                             const float* __restrict__ l1w,
                                             const float* __restrict__ l1b,
                                             const float* __restrict__ l2w,
                                             const float* __restrict__ l2b,
                                             float* __restrict__ out) {
  const int g = blockIdx.x, j = threadIdx.x;
  const float inv = __builtin_amdgcn_rcpf(fmaxf(counts[g], 1.f));
  float acc = l1b[j];
  for (int k = 0; k < HD; ++k)
    acc = fmaf(pooled[g * HD + k] * inv, l1w[k * 64 + j], acc);
  float v = fmaxf(acc, 0.f) * l2w[j];
  v = wave_allsum(v);
  if (j == 0) out[g] = v + l2b[0];
}

extern "C" void kernel_launch(void* const* d_in, const int* in_sizes, int n_in,
                              void* d_out, int out_size, void* d_ws,
                              size_t ws_size, hipStream_t stream) {
  const float* x = (const float*)d_in[0];
  const float* pos = (const float*)d_in[1];
  const int* ei = (const int*)d_in[2];
  const int* batch = (const int*)d_in[3];
  const float* gcn_w = (const float*)d_in[4];
  const float* gcn_b = (const float*)d_in[5];
  const float* pam_w = (const float*)d_in[6];
  const float* pam_b = (const float*)d_in[7];
  const float* pm_w1 = (const float*)d_in[8];
  const float* pm_b1 = (const float*)d_in[9];
  const float* pm_w2 = (const float*)d_in[10];
  const float* pm_b2 = (const float*)d_in[11];
  const float* att_w = (const float*)d_in[12];
  const float* att_b = (const float*)d_in[13];
  const float* fus_w = (const float*)d_in[14];
  const float* fus_b = (const float*)d_in[15];
  const float* l1_w = (const float*)d_in[16];
  const float* l1_b = (const float*)d_in[17];
  const float* l2_w = (const float*)d_in[18];
  const float* l2_b = (const float*)d_in[19];
  float* out = (float*)d_out;

  size_t off = 0;
  auto alloc = [&](size_t bytes) {
    void* p = (char*)d_ws + off;
    off += (bytes + 255) & ~size_t(255);
    return p;
  };
  u32* xb = (u32*)alloc((size_t)NN * 64 * 4);
  u32* ZG = (u32*)alloc((size_t)NN * 64 * 4);
  u32* XT = (u32*)alloc((size_t)NN * 128 * 4);
  u16* GLloc = (u16*)alloc((size_t)NN * 256 * 2);
  float* sa = (float*)alloc((size_t)NN * 4);
  float* dinv = (float*)alloc((size_t)NN * 4);
  float* ai = (float*)alloc((size_t)NN * 4);
  float* aj = (float*)alloc((size_t)NN * 4);
  float* pooled = (float*)alloc((size_t)NG * HD * 4);
  float* counts = (float*)alloc((size_t)NG * 4);
  int* cnt = (int*)alloc((size_t)NN * 4);   // cnt+cursor contiguous: 1 memset
  int* cursor = (int*)alloc((size_t)NN * 4);
  int* offs = (int*)alloc((size_t)NN * 4);
  int* csr_src = (int*)alloc((size_t)NE * 4);
  int* bsum = (int*)alloc((size_t)SCAN_B * 4);
  u16* Bg = (u16*)alloc((size_t)16 * 128 * 8 * 2);
  u16* Bl = (u16*)alloc((size_t)32 * 128 * 8 * 2);
  u16* Bf = (u16*)alloc((size_t)32 * 128 * 8 * 2);
  float* vi = (float*)alloc(128 * 4);
  float* vj = (float*)alloc(128 * 4);
  float* consts = (float*)alloc(2 * 4);
  float* bsumv = (float*)alloc(128 * 4);

  hipMemsetAsync(cnt, 0, ((char*)cursor - (char*)cnt) + NN * 4, stream);
  hipMemsetAsync(pooled, 0, NG * HD * 4, stream);

  k_wpack<<<41, 256, 0, stream>>>(gcn_w, pam_w, pm_w2, fus_w, pam_b, att_w,
                                  att_b, pm_b2, Bg, Bl, Bf, vi, vj, consts,
                                  bsumv);
  k_xcast<<<(NN + 3) / 4, 256, 0, stream>>>(x, vi, vj, consts, xb, ai, aj);
  k_hist<<<(NE + 255) / 256, 256, 0, stream>>>(ei, cnt);
  k_scan1<<<SCAN_B, 256, 0, stream>>>(cnt, bsum);
  k_scan2<<<1, 256, 0, stream>>>(bsum);
  k_scan3<<<SCAN_B, 256, 0, stream>>>(cnt, bsum, offs, dinv);
  k_scatter<<<(NE + 255) / 256, 256, 0, stream>>>(ei, offs, cursor, csr_src);
  k_gcounts<<<1, 256, 0, stream>>>(batch, counts);
  k_agg<<<(NN + 3) / 4, 256, 0, stream>>>(xb, pos, dinv, csr_src, offs, cnt,
                                          ai, aj, pm_w1, pm_b1, ZG, XT, sa);
  const int nb = (NN + 127) / 128;  // 391
  k_gemm_gcn<<<nb, 256, 0, stream>>>((const u16*)ZG, Bg, dinv, gcn_b, GLloc);
  k_gemm_loc<<<nb, 256, 0, stream>>>((const u16*)XT, Bl, sa, bsumv, GLloc);
  k_gemm_fus<<<nb, 256, 0, stream>>>(GLloc, Bf, fus_b, batch, pooled);
  k_head<<<NG, 64, 0, stream>>>(pooled, counts, l1_w, l1_b, l2_w, l2_b, out);
}

// Round 5
// 222.787 us; speedup vs baseline: 4.3873x; 1.1387x over previous
//
#include <hip/hip_runtime.h>
#include <math.h>

#define NN 50000
#define NE 800000
#define HD 128
#define NG 256
#define SCAN_B 196   // ceil(NN/256)
#define XCAST_B 12500  // NN/4
#define HIST_B 3125    // NE/256

typedef unsigned int u32;
typedef unsigned short u16;
typedef __attribute__((ext_vector_type(8))) short bf16x8;
typedef __attribute__((ext_vector_type(4))) float f32x4;

__device__ __forceinline__ float wave_allsum(float v) {
#pragma unroll
  for (int m = 1; m < 64; m <<= 1) v += __shfl_xor(v, m, 64);
  return v;
}
__device__ __forceinline__ float bcastf(float v, int t) {
  return __int_as_float(__builtin_amdgcn_readlane(__float_as_int(v), t));
}
__device__ __forceinline__ u32 f2b_bits(float f) {  // RNE float->bf16 bits
  u32 u = __float_as_uint(f);
  return (u + 0x7fffu + ((u >> 16) & 1u)) >> 16;
}
__device__ __forceinline__ u32 pack2(float lo, float hi) {
  return f2b_bits(lo) | (f2b_bits(hi) << 16);
}

// ---- pack weights to MFMA B-fragment layout (blocks 0..39); block 40 =
//      prevec: vi = pam_w@wi, vj = pam_w@wj, consts, bsum = pam_b + pm_b2 ----
__global__ __launch_bounds__(256) void k_wpack(
    const float* __restrict__ gcn_w, const float* __restrict__ pam_w,
    const float* __restrict__ pm_w2, const float* __restrict__ fus_w,
    const float* __restrict__ pam_b, const float* __restrict__ att_w,
    const float* __restrict__ att_b, const float* __restrict__ pm_b2,
    u16* __restrict__ Bg, u16* __restrict__ Bl, u16* __restrict__ Bf,
    float* __restrict__ vi, float* __restrict__ vj,
    float* __restrict__ consts, float* __restrict__ bsum) {
  if (blockIdx.x == 40) {  // prevec
    const int t = threadIdx.x;
    const int k = t & 127;
    const float* w = att_w + (t >> 7) * HD;
    float s = 0.f;
    for (int h = 0; h < HD; ++h) s = fmaf(pam_w[k * HD + h], w[h], s);
    if (t < 128) {
      vi[k] = s;
      bsum[k] = pam_b[k] + pm_b2[k];
    } else {
      vj[k] = s;
    }
    if (t < 64) {
      float p = fmaf(pam_b[t], att_w[t], pam_b[t + 64] * att_w[t + 64]);
      p = wave_allsum(p);
      if (t == 0) consts[0] = p + att_b[0];
    } else if (t < 128) {
      const int l = t - 64;
      float p =
          fmaf(pam_b[l], att_w[HD + l], pam_b[l + 64] * att_w[HD + 64 + l]);
      p = wave_allsum(p);
      if (l == 0) consts[1] = p;
    }
    return;
  }
  const int t = blockIdx.x * 256 + threadIdx.x;
  const float* W;
  u16* dst;
  if (t < 2048) {  // gcn_w: K=128 -> 16 kb
    const int kb = t >> 7, n = t & 127;
    W = gcn_w + (size_t)kb * 8 * HD + n;
    dst = Bg + (size_t)t * 8;
  } else if (t < 6144) {  // [pam_w; pm_w2]: K=256 -> 32 kb
    const int u = t - 2048;
    const int kb = u >> 7, n = u & 127;
    W = ((kb < 16) ? (pam_w + (size_t)kb * 8 * HD)
                   : (pm_w2 + (size_t)(kb - 16) * 8 * HD)) +
        n;
    dst = Bl + (size_t)u * 8;
  } else {  // fus_w: K=256 -> 32 kb
    const int u = t - 6144;
    const int kb = u >> 7, n = u & 127;
    W = fus_w + (size_t)kb * 8 * HD + n;
    dst = Bf + (size_t)u * 8;
  }
  union {
    u16 o[8];
    uint4 v;
  } pk;
#pragma unroll
  for (int i = 0; i < 8; ++i) pk.o[i] = (u16)f2b_bits(W[i * HD]);
  *(uint4*)dst = pk.v;
}

// ---- merged: x->bf16 + att dots (blocks < XCAST_B) ; degree hist (rest) ----
__global__ __launch_bounds__(256) void k_pre2(
    const float* __restrict__ x, const float* __restrict__ vi,
    const float* __restrict__ vj, const float* __restrict__ consts,
    const int* __restrict__ ei, u32* __restrict__ xb, float* __restrict__ ai,
    float* __restrict__ aj, int* __restrict__ cnt) {
  if (blockIdx.x < XCAST_B) {
    const int wave = threadIdx.x >> 6, lane = threadIdx.x & 63;
    const int i = blockIdx.x * 4 + wave;
    if (i >= NN) return;
    const float2 v = *(const float2*)&x[(size_t)i * HD + lane * 2];
    xb[(size_t)i * 64 + lane] = pack2(v.x, v.y);
    const float2 a = *(const float2*)&vi[lane * 2];
    const float2 b = *(const float2*)&vj[lane * 2];
    float si = wave_allsum(fmaf(v.x, a.x, v.y * a.y));
    float sj = wave_allsum(fmaf(v.x, b.x, v.y * b.y));
    if (lane == 0) {
      ai[i] = si + consts[0];
      aj[i] = sj + consts[1];
    }
  } else {
    const int e = (blockIdx.x - XCAST_B) * 256 + threadIdx.x;
    if (e < NE) atomicAdd(&cnt[ei[NE + e]], 1);
  }
}

// hierarchical scan
__global__ __launch_bounds__(256) void k_scan1(const int* __restrict__ cnt,
                                               int* __restrict__ bsum) {
  const int i = blockIdx.x * 256 + threadIdx.x;
  int v = (i < NN) ? cnt[i] : 0;
#pragma unroll
  for (int m = 1; m < 64; m <<= 1) v += __shfl_xor(v, m, 64);
  __shared__ int s[4];
  if ((threadIdx.x & 63) == 0) s[threadIdx.x >> 6] = v;
  __syncthreads();
  if (threadIdx.x == 0) bsum[blockIdx.x] = s[0] + s[1] + s[2] + s[3];
}

__global__ __launch_bounds__(256) void k_scan2(int* __restrict__ bsum) {
  __shared__ int s[256];
  const int t = threadIdx.x;
  const int v = (t < SCAN_B) ? bsum[t] : 0;
  s[t] = v;
  __syncthreads();
  for (int d = 1; d < 256; d <<= 1) {
    int add = (t >= d) ? s[t - d] : 0;
    __syncthreads();
    s[t] += add;
    __syncthreads();
  }
  if (t < SCAN_B) bsum[t] = s[t] - v;  // exclusive
}

// scan3 + dinv + adj2 (aj,dinv) + pos4 repack
__global__ __launch_bounds__(256) void k_scan3(
    const int* __restrict__ cnt, const int* __restrict__ bsum,
    const float* __restrict__ aj, const float* __restrict__ pos,
    int* __restrict__ offs, float2* __restrict__ adj2,
    float4* __restrict__ pos4) {
  const int t = threadIdx.x;
  const int i = blockIdx.x * 256 + t;
  const int v = (i < NN) ? cnt[i] : 0;
  __shared__ int s[256];
  s[t] = v;
  __syncthreads();
  for (int d = 1; d < 256; d <<= 1) {
    int add = (t >= d) ? s[t - d] : 0;
    __syncthreads();
    s[t] += add;
    __syncthreads();
  }
  if (i < NN) {
    offs[i] = bsum[blockIdx.x] + s[t] - v;
    const float dv = __builtin_amdgcn_rsqf((float)v + 1.0f);
    adj2[i] = make_float2(aj[i], dv);
    pos4[i] =
        make_float4(pos[3 * i], pos[3 * i + 1], pos[3 * i + 2], 0.f);
  }
}

// ---- merged: CSR scatter (blocks < HIST_B) + graph counts (last block) ----
__global__ __launch_bounds__(256) void k_scatgc(
    const int* __restrict__ ei, const int* __restrict__ offs,
    int* __restrict__ cursor, int* __restrict__ csr_src,
    const int* __restrict__ batch, float* __restrict__ counts) {
  if (blockIdx.x < HIST_B) {
    const int e = blockIdx.x * 256 + threadIdx.x;
    if (e < NE) {
      const int d = ei[NE + e];
      const int slot = atomicAdd(&cursor[d], 1);
      csr_src[offs[d] + slot] = ei[e];
    }
  } else {
    const int g = threadIdx.x;
    int lo = 0, hi = NN;
    while (lo < hi) {
      const int mid = (lo + hi) >> 1;
      if (batch[mid] < g) lo = mid + 1; else hi = mid;
    }
    const int b0 = lo;
    hi = NN;
    while (lo < hi) {
      const int mid = (lo + hi) >> 1;
      if (batch[mid] <= g) lo = mid + 1; else hi = mid;
    }
    counts[g] = (float)(lo - b0);
  }
}

// ---------------- per-node edge aggregation (1 wave / node) ----------------
__global__ __launch_bounds__(256) void k_agg(
    const u32* __restrict__ xb, const float4* __restrict__ pos4,
    const float2* __restrict__ adj2, const int* __restrict__ csr_src,
    const int* __restrict__ offs, const int* __restrict__ cnt,
    const float* __restrict__ ai_arr, const float* __restrict__ pm_w1,
    const float* __restrict__ pm_b1, u32* __restrict__ ZG,
    u32* __restrict__ XT, float* __restrict__ sa_out) {
  const int wave = threadIdx.x >> 6, lane = threadIdx.x & 63;
  const int i = blockIdx.x * 4 + wave;
  if (i >= NN) return;
  const int c0 = lane * 2;

  const float2 w1x = *(const float2*)&pm_w1[c0];
  const float2 w1y = *(const float2*)&pm_w1[HD + c0];
  const float2 w1z = *(const float2*)&pm_w1[2 * HD + c0];
  const float2 b1 = *(const float2*)&pm_b1[c0];
  const float ai = ai_arr[i];
  const float4 pi = pos4[i];
  const float di = adj2[i].y;

  float2 zg = {0.f, 0.f}, xa = {0.f, 0.f}, tt = {0.f, 0.f};
  float sa = 0.f;
  const int b = offs[i], e = b + cnt[i];
  for (int base = b; base < e; base += 64) {
    const int mm = min(64, e - base);
    const int sk = csr_src[base + ((lane < mm) ? lane : 0)];
    const float2 a2 = adj2[sk];  // {aj, dinv}
    float attk = __builtin_amdgcn_rcpf(1.f + __expf(-(ai + a2.x)));
    const float dsk = a2.y;
    const float4 ps = pos4[sk];
    const float dxk = pi.x - ps.x;
    const float dyk = pi.y - ps.y;
    const float dzk = pi.z - ps.z;
    if (lane >= mm) attk = 0.f;
    sa += wave_allsum(attk);

    auto body = [&](int T) {
      const int s = __builtin_amdgcn_readlane(sk, T);
      const float att = bcastf(attk, T);
      const float ds = bcastf(dsk, T);
      const float dx = bcastf(dxk, T);
      const float dy = bcastf(dyk, T);
      const float dz = bcastf(dzk, T);
      const u32 xr = xb[(size_t)s * 64 + lane];
      const float xj0 = __uint_as_float(xr << 16);
      const float xj1 = __uint_as_float(xr & 0xffff0000u);
      zg.x = fmaf(ds, xj0, zg.x);
      zg.y = fmaf(ds, xj1, zg.y);
      xa.x = fmaf(att, xj0, xa.x);
      xa.y = fmaf(att, xj1, xa.y);
      const float g0 =
          fmaxf(fmaf(dz, w1z.x, fmaf(dy, w1y.x, fmaf(dx, w1x.x, b1.x))), 0.f);
      const float g1 =
          fmaxf(fmaf(dz, w1z.y, fmaf(dy, w1y.y, fmaf(dx, w1x.y, b1.y))), 0.f);
      tt.x = fmaf(att, g0, tt.x);
      tt.y = fmaf(att, g1, tt.y);
    };
    int t = 0;
    for (; t + 4 <= mm; t += 4) {
      body(t);
      body(t + 1);
      body(t + 2);
      body(t + 3);
    }
    for (; t < mm; ++t) body(t);
  }
  const u32 xi = xb[(size_t)i * 64 + lane];
  zg.x = fmaf(di, __uint_as_float(xi << 16), zg.x);
  zg.y = fmaf(di, __uint_as_float(xi & 0xffff0000u), zg.y);

  ZG[(size_t)i * 64 + lane] = pack2(zg.x, zg.y);
  XT[(size_t)i * 128 + lane] = pack2(xa.x, xa.y);
  XT[(size_t)i * 128 + 64 + lane] = pack2(tt.x, tt.y);
  if (lane == 0) sa_out[i] = sa;
}

// ---------------- LDS-free MFMA bf16 GEMM core (global A) ----------------
__device__ __forceinline__ void mfma_loop(const u16* __restrict__ A, int K,
                                          const u16* __restrict__ Bp,
                                          f32x4 acc[2][8], int n0) {
  const int lane = threadIdx.x & 63;
  const int wid = threadIdx.x >> 6;
  const int m = lane & 15, g = lane >> 4;
  const int rA0 = min(n0 + wid * 32 + m, NN - 1);
  const int rA1 = min(n0 + wid * 32 + 16 + m, NN - 1);
  const u16* pa0 = A + (size_t)rA0 * K + g * 8;
  const u16* pa1 = A + (size_t)rA1 * K + g * 8;
  const u16* pb0 = Bp + ((size_t)g * HD + m) * 8;
  for (int k0 = 0; k0 < K; k0 += 32) {
    const bf16x8 a0 = *(const bf16x8*)(pa0 + k0);
    const bf16x8 a1 = *(const bf16x8*)(pa1 + k0);
    const u16* pb = pb0 + (size_t)(k0 >> 3) * HD * 8;
#pragma unroll
    for (int cf = 0; cf < 8; ++cf) {
      const bf16x8 b = *(const bf16x8*)(pb + cf * 16 * 8);
      acc[0][cf] =
          __builtin_amdgcn_mfma_f32_16x16x32_bf16(a0, b, acc[0][cf], 0, 0, 0);
      acc[1][cf] =
          __builtin_amdgcn_mfma_f32_16x16x32_bf16(a1, b, acc[1][cf], 0, 0, 0);
    }
  }
}

// ---- fused dense tail: G1 (gcn) + G2 (local) -> swizzled LDS bf16 tile,
//      G3 (fusion) from LDS, then segment pooling. One block = 128 rows. ----
__global__ __launch_bounds__(256) void k_gemms(
    const u16* __restrict__ ZG, const u16* __restrict__ XT,
    const u16* __restrict__ Bg, const u16* __restrict__ Bl,
    const u16* __restrict__ Bf, const float2* __restrict__ adj2,
    const float* __restrict__ sa, const float* __restrict__ gcn_b,
    const float* __restrict__ bsumv, const float* __restrict__ fus_b,
    const int* __restrict__ batch, float* __restrict__ pooled) {
  __shared__ u16 T[128 * 256];  // bf16 [gl|local], XOR-swizzled in 16B units
  __shared__ int batch_lds[128];
  const int n0 = blockIdx.x * 128;
  const int t = threadIdx.x, lane = t & 63, wid = t >> 6;
  const int m = lane & 15, g = lane >> 4;
  f32x4 acc[2][8];

  // ---- phase A: gl = relu(dinv*(ZG@gcn_w) + gcn_b) -> T cols 0..127 ----
#pragma unroll
  for (int rf = 0; rf < 2; ++rf)
#pragma unroll
    for (int cf = 0; cf < 8; ++cf) acc[rf][cf] = (f32x4){0.f, 0.f, 0.f, 0.f};
  mfma_loop(ZG, 128, Bg, acc, n0);
  {
    float bv[8];
#pragma unroll
    for (int cf = 0; cf < 8; ++cf) bv[cf] = gcn_b[cf * 16 + m];
#pragma unroll
    for (int rf = 0; rf < 2; ++rf)
#pragma unroll
      for (int j = 0; j < 4; ++j) {
        const int rl = wid * 32 + rf * 16 + g * 4 + j;
        const float dv = adj2[min(n0 + rl, NN - 1)].y;
#pragma unroll
        for (int cf = 0; cf < 8; ++cf) {
          const float v = fmaxf(fmaf(dv, acc[rf][cf][j], bv[cf]), 0.f);
          T[rl * 256 + ((cf * 16 + m) ^ ((rl & 7) << 3))] = (u16)f2b_bits(v);
        }
      }
  }
  // ---- phase B: local = relu(XT@Bl + sa*bsum) -> T cols 128..255 ----
#pragma unroll
  for (int rf = 0; rf < 2; ++rf)
#pragma unroll
    for (int cf = 0; cf < 8; ++cf) acc[rf][cf] = (f32x4){0.f, 0.f, 0.f, 0.f};
  mfma_loop(XT, 256, Bl, acc, n0);
  {
    float bv[8];
#pragma unroll
    for (int cf = 0; cf < 8; ++cf) bv[cf] = bsumv[cf * 16 + m];
#pragma unroll
    for (int rf = 0; rf < 2; ++rf)
#pragma unroll
      for (int j = 0; j < 4; ++j) {
        const int rl = wid * 32 + rf * 16 + g * 4 + j;
        const float sv = sa[min(n0 + rl, NN - 1)];
#pragma unroll
        for (int cf = 0; cf < 8; ++cf) {
          const float v = fmaxf(fmaf(sv, bv[cf], acc[rf][cf][j]), 0.f);
          T[rl * 256 + ((128 + cf * 16 + m) ^ ((rl & 7) << 3))] =
              (u16)f2b_bits(v);
        }
      }
  }
  if (t < 128) batch_lds[t] = (n0 + t < NN) ? batch[n0 + t] : -1;
  __syncthreads();

  // ---- phase C: fused = relu([gl|local]@fus_w + fus_b), A-frags from LDS --
#pragma unroll
  for (int rf = 0; rf < 2; ++rf)
#pragma unroll
    for (int cf = 0; cf < 8; ++cf) acc[rf][cf] = (f32x4){0.f, 0.f, 0.f, 0.f};
  {
    const int rA0 = wid * 32 + m, rA1 = rA0 + 16;
    const int x0 = (rA0 & 7) << 3;  // same for rA1 (rA1 = rA0+16)
    const u16* pb0 = Bf + ((size_t)g * HD + m) * 8;
#pragma unroll
    for (int k0 = 0; k0 < 256; k0 += 32) {
      const int cA = k0 + g * 8;
      const bf16x8 a0 = *(const bf16x8*)&T[rA0 * 256 + (cA ^ x0)];
      const bf16x8 a1 = *(const bf16x8*)&T[rA1 * 256 + (cA ^ x0)];
      const u16* pb = pb0 + (size_t)(k0 >> 3) * HD * 8;
#pragma unroll
      for (int cf = 0; cf < 8; ++cf) {
        const bf16x8 b = *(const bf16x8*)(pb + cf * 16 * 8);
        acc[0][cf] =
            __builtin_amdgcn_mfma_f32_16x16x32_bf16(a0, b, acc[0][cf], 0, 0, 0);
        acc[1][cf] =
            __builtin_amdgcn_mfma_f32_16x16x32_bf16(a1, b, acc[1][cf], 0, 0, 0);
      }
    }
  }
  __syncthreads();  // all LDS reads done; reuse T as f32 fused tile
  float* F = (float*)T;  // [128][128] f32 = 64KB
  {
    float bv[8];
#pragma unroll
    for (int cf = 0; cf < 8; ++cf) bv[cf] = fus_b[cf * 16 + m];
#pragma unroll
    for (int rf = 0; rf < 2; ++rf)
#pragma unroll
      for (int j = 0; j < 4; ++j) {
        const int rl = wid * 32 + rf * 16 + g * 4 + j;
#pragma unroll
        for (int cf = 0; cf < 8; ++cf)
          F[rl * 128 + cf * 16 + m] = fmaxf(acc[rf][cf][j] + bv[cf], 0.f);
      }
  }
  __syncthreads();

  // ---- segment pooling over sorted batch ids ----
  const int col = t & 127;
  const int r0 = (t >> 7) * 64, r1 = r0 + 64;
  int seg = -1;
  float run = 0.f;
  for (int r = r0; r < r1; ++r) {
    const int bg = batch_lds[r];
    const float v = F[r * 128 + col];
    if (bg != seg) {
      if (seg >= 0) atomicAdd(&pooled[seg * HD + col], run);
      seg = bg;
      run = 0.f;
    }
    if (bg >= 0) run += v;
  }
  if (seg >= 0) atomicAdd(&pooled[seg * HD + col], run);
}

// ---------------- head: out = relu(pooled/cnt @ l1)@l2 ----------------
__global__ __launch_bounds__(64) void k_head(const float* __restrict__ pooled,
                                             const float* __restrict__ counts,
                                             const float* __restrict__ l1w,
                                             const float* __restrict__ l1b,
                                             const float* __restrict__ l2w,
                                             const float* __restrict__ l2b,
                                             float* __restrict__ out) {
  const int g = blockIdx.x, j = threadIdx.x;
  const float inv = __builtin_amdgcn_rcpf(fmaxf(counts[g], 1.f));
  float acc = l1b[j];
  for (int k = 0; k < HD; ++k)
    acc = fmaf(pooled[g * HD + k] * inv, l1w[k * 64 + j], acc);
  float v = fmaxf(acc, 0.f) * l2w[j];
  v = wave_allsum(v);
  if (j == 0) out[g] = v + l2b[0];
}

extern "C" void kernel_launch(void* const* d_in, const int* in_sizes, int n_in,
                              void* d_out, int out_size, void* d_ws,
                              size_t ws_size, hipStream_t stream) {
  const float* x = (const float*)d_in[0];
  const float* pos = (const float*)d_in[1];
  const int* ei = (const int*)d_in[2];
  const int* batch = (const int*)d_in[3];
  const float* gcn_w = (const float*)d_in[4];
  const float* gcn_b = (const float*)d_in[5];
  const float* pam_w = (const float*)d_in[6];
  const float* pam_b = (const float*)d_in[7];
  const float* pm_w1 = (const float*)d_in[8];
  const float* pm_b1 = (const float*)d_in[9];
  const float* pm_w2 = (const float*)d_in[10];
  const float* pm_b2 = (const float*)d_in[11];
  const float* att_w = (const float*)d_in[12];
  const float* att_b = (const float*)d_in[13];
  const float* fus_w = (const float*)d_in[14];
  const float* fus_b = (const float*)d_in[15];
  const float* l1_w = (const float*)d_in[16];
  const float* l1_b = (const float*)d_in[17];
  const float* l2_w = (const float*)d_in[18];
  const float* l2_b = (const float*)d_in[19];
  float* out = (float*)d_out;

  size_t off = 0;
  auto alloc = [&](size_t bytes) {
    void* p = (char*)d_ws + off;
    off += (bytes + 255) & ~size_t(255);
    return p;
  };
  u32* xb = (u32*)alloc((size_t)NN * 64 * 4);
  u32* ZG = (u32*)alloc((size_t)NN * 64 * 4);
  u32* XT = (u32*)alloc((size_t)NN * 128 * 4);
  float* sa = (float*)alloc((size_t)NN * 4);
  float* ai = (float*)alloc((size_t)NN * 4);
  float* aj = (float*)alloc((size_t)NN * 4);
  float2* adj2 = (float2*)alloc((size_t)NN * 8);
  float4* pos4 = (float4*)alloc((size_t)NN * 16);
  float* pooled = (float*)alloc((size_t)NG * HD * 4);
  float* counts = (float*)alloc((size_t)NG * 4);
  int* cnt = (int*)alloc((size_t)NN * 4);  // cnt+cursor contiguous: 1 memset
  int* cursor = (int*)alloc((size_t)NN * 4);
  int* offs = (int*)alloc((size_t)NN * 4);
  int* csr_src = (int*)alloc((size_t)NE * 4);
  int* bsum = (int*)alloc((size_t)SCAN_B * 4);
  u16* Bg = (u16*)alloc((size_t)16 * 128 * 8 * 2);
  u16* Bl = (u16*)alloc((size_t)32 * 128 * 8 * 2);
  u16* Bf = (u16*)alloc((size_t)32 * 128 * 8 * 2);
  float* vi = (float*)alloc(128 * 4);
  float* vj = (float*)alloc(128 * 4);
  float* consts = (float*)alloc(2 * 4);
  float* bsumv = (float*)alloc(128 * 4);

  hipMemsetAsync(cnt, 0, ((char*)cursor - (char*)cnt) + NN * 4, stream);
  hipMemsetAsync(pooled, 0, NG * HD * 4, stream);

  k_wpack<<<41, 256, 0, stream>>>(gcn_w, pam_w, pm_w2, fus_w, pam_b, att_w,
                                  att_b, pm_b2, Bg, Bl, Bf, vi, vj, consts,
                                  bsumv);
  k_pre2<<<XCAST_B + HIST_B, 256, 0, stream>>>(x, vi, vj, consts, ei, xb, ai,
                                               aj, cnt);
  k_scan1<<<SCAN_B, 256, 0, stream>>>(cnt, bsum);
  k_scan2<<<1, 256, 0, stream>>>(bsum);
  k_scan3<<<SCAN_B, 256, 0, stream>>>(cnt, bsum, aj, pos, offs, adj2, pos4);
  k_scatgc<<<HIST_B + 1, 256, 0, stream>>>(ei, offs, cursor, csr_src, batch,
                                           counts);
  k_agg<<<XCAST_B, 256, 0, stream>>>(xb, pos4, adj2, csr_src, offs, cnt, ai,
                                     pm_w1, pm_b1, ZG, XT, sa);
  const int nb = (NN + 127) / 128;  // 391
  k_gemms<<<nb, 256, 0, stream>>>((const u16*)ZG, (const u16*)XT, Bg, Bl, Bf,
                                  adj2, sa, gcn_b, bsumv, fus_b, batch,
                                  pooled);
  k_head<<<NG, 64, 0, stream>>>(pooled, counts, l1_w, l1_b, l2_w, l2_b, out);
}